// Round 4
// baseline (17099.300 us; speedup 1.0000x reference)
//
#include <hip/hip_runtime.h>

// ---------------------------------------------------------------- encoder
__global__ __launch_bounds__(256) void encoder_kernel(
    const float* __restrict__ xc, const float* __restrict__ yc, const float* __restrict__ xt,
    const float* __restrict__ W1, const float* __restrict__ b1,
    const float* __restrict__ W2, const float* __restrict__ b2,
    float* __restrict__ z)
{
  __shared__ float zin[10];
  __shared__ float hid[256];
  int blk = blockIdx.x; int b = blk>>10; int t = blk & 1023;
  int tid = threadIdx.x;
  if (tid < 10){
    float v;
    if (tid < 8)      v = (t<512) ? xc[((size_t)b*512+t)*8+tid] : xt[((size_t)b*512+(t-512))*8+tid];
    else if (tid==8)  v = (t<512) ? yc[(size_t)b*512+t] : 0.f;
    else              v = (t<512) ? 0.f : 1.f;
    zin[tid]=v;
  }
  __syncthreads();
  float s = b1[tid];
  #pragma unroll
  for (int i=0;i<10;i++) s += zin[i]*W1[i*256+tid];
  hid[tid] = fmaxf(s, 0.f);
  __syncthreads();
  float o = b2[tid];
  for (int j=0;j<256;j++) o += hid[j]*W2[j*256+tid];
  z[((size_t)b*1024+t)*256 + tid] = o;
}

// ---------------------------------------------------------------- layernorm
__global__ __launch_bounds__(256) void ln_fast(const float* __restrict__ z,
    const float* __restrict__ g, const float* __restrict__ be, float* __restrict__ h)
{
  __shared__ float red[256];
  int row = blockIdx.x, tid = threadIdx.x;
  float x = z[(size_t)row*256 + tid];
  red[tid] = x; __syncthreads();
  for (int s=128; s>0; s>>=1){ if (tid<s) red[tid]+=red[tid+s]; __syncthreads(); }
  float mu = red[0] * (1.f/256.f); __syncthreads();
  float d = x - mu;
  red[tid] = d*d; __syncthreads();
  for (int s=128; s>0; s>>=1){ if (tid<s) red[tid]+=red[tid+s]; __syncthreads(); }
  float var = red[0] * (1.f/256.f);
  float r = rsqrtf(var + 1e-5f);
  h[(size_t)row*256+tid] = d*r*g[tid] + be[tid];
}

// ---------------------------------------------------------------- gemm_v2
// out[M x N] = EPI(A[M x K] @ B[K x N] + bias)
// EPI 0: plain ; 1: relu ; 2: + resid (out may alias resid)
// BM=128 fixed, BN in {128,64}, micro-tile 8x(BN/16), BK=16, 256 threads.
// Register-prefetch double-buffered LDS: ONE barrier per K-tile (v1 had two),
// 64 FMA per 4 ds_read_b128 (v1: 16 per 2). Lane map: wave = 8x8 lane grid so
// A/B LDS reads alias <=2-way (free). Requires M%128==0, N%BN==0, K%16==0.
template<int BN, int EPI>
__global__ __launch_bounds__(256, 4) void gemm_v2(
    const float* __restrict__ A, const float* __restrict__ B,
    const float* __restrict__ bias, const float* __restrict__ resid,
    float* __restrict__ out, int N, int K)
{
  constexpr int BM = 128, BK = 16;
  constexpr int TN = BN/16;            // 8 or 4
  constexpr int LDA = BM + 4;          // 132: k-stride stays 16B-aligned
  constexpr int LDB = BN + 4;          // 132 / 68: both 16B-aligned strides
  __shared__ float As[2][BK*LDA];
  __shared__ float Bs[2][BK*LDB];

  const int tid = threadIdx.x;
  const int wv = tid >> 6, ln = tid & 63;
  const int trow = ((wv>>1)<<3) + (ln>>3);   // 0..15 (8 rows each)
  const int tcol = ((wv&1)<<3) + (ln&7);     // 0..15 (TN cols each)
  const int m0 = blockIdx.y*BM, n0 = blockIdx.x*BN;

  // A stage: thread loads rows (ar, ar+64), cols ac..ac+3 of the 128x16 slab
  const int ar = tid>>2, ac = (tid&3)<<2;
  // B stage: BN=128: rows (br, br+8), 2 float4; BN=64: row br, 1 float4
  const int br = (BN==128) ? (tid>>5) : (tid>>4);
  const int bc = (BN==128) ? ((tid&31)<<2) : ((tid&15)<<2);

  const float* Ap = &A[(size_t)(m0+ar)*K + ac];
  const float* Bp = &B[(size_t)br*N + n0 + bc];

  float4 pa0, pa1, pb0, pb1;
  pa0 = *(const float4*)&Ap[0];
  pa1 = *(const float4*)&Ap[(size_t)64*K];
  pb0 = *(const float4*)&Bp[0];
  if (BN==128) pb1 = *(const float4*)&Bp[(size_t)8*N];

  {
    float* as = As[0]; float* bs = Bs[0];
    as[(ac+0)*LDA+ar]    = pa0.x; as[(ac+1)*LDA+ar]    = pa0.y;
    as[(ac+2)*LDA+ar]    = pa0.z; as[(ac+3)*LDA+ar]    = pa0.w;
    as[(ac+0)*LDA+ar+64] = pa1.x; as[(ac+1)*LDA+ar+64] = pa1.y;
    as[(ac+2)*LDA+ar+64] = pa1.z; as[(ac+3)*LDA+ar+64] = pa1.w;
    *(float4*)&bs[br*LDB+bc] = pb0;
    if (BN==128) *(float4*)&bs[(br+8)*LDB+bc] = pb1;
  }
  __syncthreads();

  float acc[8][TN] = {};
  const int NT = K/BK;
  int cur = 0;
  for (int t=0; t<NT; ++t){
    if (t+1 < NT){
      const float* Ap2 = Ap + (t+1)*BK;
      pa0 = *(const float4*)&Ap2[0];
      pa1 = *(const float4*)&Ap2[(size_t)64*K];
      const float* Bp2 = Bp + (size_t)(t+1)*BK*N;
      pb0 = *(const float4*)&Bp2[0];
      if (BN==128) pb1 = *(const float4*)&Bp2[(size_t)8*N];
    }
    const float* as = As[cur]; const float* bs = Bs[cur];
    #pragma unroll
    for (int k=0;k<BK;k++){
      float4 x0 = *(const float4*)&as[k*LDA + trow*8];
      float4 x1 = *(const float4*)&as[k*LDA + trow*8 + 4];
      float av[8] = {x0.x,x0.y,x0.z,x0.w, x1.x,x1.y,x1.z,x1.w};
      float bv[TN];
      {
        float4 y0 = *(const float4*)&bs[k*LDB + tcol*TN];
        bv[0]=y0.x; bv[1]=y0.y; bv[2]=y0.z; bv[3]=y0.w;
        if (BN==128){
          float4 y1 = *(const float4*)&bs[k*LDB + tcol*TN + 4];
          bv[4]=y1.x; bv[5]=y1.y; bv[6]=y1.z; bv[7]=y1.w;
        }
      }
      #pragma unroll
      for (int i=0;i<8;i++)
        #pragma unroll
        for (int j=0;j<TN;j++)
          acc[i][j] += av[i]*bv[j];
    }
    if (t+1 < NT){
      float* as2 = As[cur^1]; float* bs2 = Bs[cur^1];
      as2[(ac+0)*LDA+ar]    = pa0.x; as2[(ac+1)*LDA+ar]    = pa0.y;
      as2[(ac+2)*LDA+ar]    = pa0.z; as2[(ac+3)*LDA+ar]    = pa0.w;
      as2[(ac+0)*LDA+ar+64] = pa1.x; as2[(ac+1)*LDA+ar+64] = pa1.y;
      as2[(ac+2)*LDA+ar+64] = pa1.z; as2[(ac+3)*LDA+ar+64] = pa1.w;
      *(float4*)&bs2[br*LDB+bc] = pb0;
      if (BN==128) *(float4*)&bs2[(br+8)*LDB+bc] = pb1;
    }
    __syncthreads();
    cur ^= 1;
  }

  // epilogue
  #pragma unroll
  for (int j4=0; j4<TN/4; ++j4){
    const int gc0 = n0 + tcol*TN + j4*4;
    float4 bsv = *(const float4*)&bias[gc0];
    float bb[4] = {bsv.x,bsv.y,bsv.z,bsv.w};
    #pragma unroll
    for (int i=0;i<8;i++){
      int gr = m0 + trow*8 + i;
      size_t off = (size_t)gr*N + gc0;
      float v0=acc[i][j4*4+0]+bb[0], v1=acc[i][j4*4+1]+bb[1];
      float v2=acc[i][j4*4+2]+bb[2], v3=acc[i][j4*4+3]+bb[3];
      if (EPI==1){ v0=fmaxf(v0,0.f); v1=fmaxf(v1,0.f); v2=fmaxf(v2,0.f); v3=fmaxf(v3,0.f); }
      if (EPI==2){ float4 rv = *(const float4*)&resid[off]; v0+=rv.x; v1+=rv.y; v2+=rv.z; v3+=rv.w; }
      float4 o; o.x=v0; o.y=v1; o.z=v2; o.w=v3;
      *(float4*)&out[off] = o;
    }
  }
}

// ---------------------------------------------------------------- attention v5
// One thread = one full (q,h) row; Q[32] and acc[32] in registers.
// Whole K/V head-slice (512 keys x 32 dims x 2) staged once in LDS (128 KB).
// All lanes of a wave process the same key in lockstep -> every LDS read is a
// same-address broadcast (conflict-free); the 32-dot is entirely in-lane:
// ZERO cross-lane ops and ZERO global loads in the inner loop.
// Block = 512 threads: tid<256 -> keys 0..255 (kg0), tid>=256 -> keys 256..511
// (kg1), same 256 q-rows; the two online-softmax halves merge through LDS.
// Grid = (4 qgroups, 8 h, 8 b) = 256 blocks = 1 block/CU (2 waves/SIMD).
// Targets (q>=512 <=> qg>=2) self-attend; handled once by kg1.
__global__ __launch_bounds__(512, 2) void attn_v5(
    const float* __restrict__ qkv, float* __restrict__ o)
{
  __shared__ float Ks[512*32];   // 64 KB
  __shared__ float Vs[512*32];   // 64 KB
  const int tid = threadIdx.x;
  const int qg = blockIdx.x, h = blockIdx.y, b = blockIdx.z;
  const int qi = tid & 255;
  const int kg = tid >> 8;             // 0: keys 0..255, 1: keys 256..511
  const int q  = qg*256 + qi;
  const float* base = qkv + (size_t)b*1024*768;
  const int hoff = h*32;
  const float sc = 0.17677669529663687f;   // 1/sqrt(32)

  // ---- stage K,V (all 512 keys) into LDS, coalesced (8 lanes x 16B per row)
  #pragma unroll
  for (int t = 0; t < 8; ++t){
    int i = tid + t*512;               // 0..4095
    int row = i >> 3, c4 = (i & 7)*4;
    *(float4*)&Ks[row*32 + c4] = *(const float4*)&base[(size_t)row*768 + 256 + hoff + c4];
  }
  #pragma unroll
  for (int t = 0; t < 8; ++t){
    int i = tid + t*512;
    int row = i >> 3, c4 = (i & 7)*4;
    *(float4*)&Vs[row*32 + c4] = *(const float4*)&base[(size_t)row*768 + 512 + hoff + c4];
  }

  // ---- load Q (scaled)
  float Q[32];
  {
    const float4* qp = (const float4*)&base[(size_t)q*768 + hoff];
    #pragma unroll
    for (int p=0;p<8;p++){
      float4 t = qp[p];
      Q[p*4+0]=t.x*sc; Q[p*4+1]=t.y*sc; Q[p*4+2]=t.z*sc; Q[p*4+3]=t.w*sc;
    }
  }
  __syncthreads();

  float m = -1e30f, l = 0.f;
  float acc[32];
  #pragma unroll
  for (int d=0;d<32;d++) acc[d]=0.f;

  const int j0 = kg*256;
  for (int jj=0; jj<256; jj+=2){
    const float* k0 = &Ks[(j0+jj)*32];
    const float* k1 = &Ks[(j0+jj+1)*32];
    float s00=0.f,s01=0.f,s02=0.f,s03=0.f, s10=0.f,s11=0.f,s12=0.f,s13=0.f;
    #pragma unroll
    for (int p=0;p<8;p++){
      float4 a = *(const float4*)&k0[p*4];
      float4 c = *(const float4*)&k1[p*4];
      s00 += Q[p*4+0]*a.x; s01 += Q[p*4+1]*a.y;
      s02 += Q[p*4+2]*a.z; s03 += Q[p*4+3]*a.w;
      s10 += Q[p*4+0]*c.x; s11 += Q[p*4+1]*c.y;
      s12 += Q[p*4+2]*c.z; s13 += Q[p*4+3]*c.w;
    }
    float d0 = (s00+s01)+(s02+s03);
    float d1 = (s10+s11)+(s12+s13);
    float mn = fmaxf(m, fmaxf(d0,d1));
    float corr = __expf(m-mn);
    float p0 = __expf(d0-mn), p1 = __expf(d1-mn);
    l = l*corr + p0 + p1;
    const float* v0 = &Vs[(j0+jj)*32];
    const float* v1 = &Vs[(j0+jj+1)*32];
    #pragma unroll
    for (int p=0;p<8;p++){
      float4 e = *(const float4*)&v0[p*4];
      float4 f = *(const float4*)&v1[p*4];
      acc[p*4+0] = acc[p*4+0]*corr + p0*e.x + p1*f.x;
      acc[p*4+1] = acc[p*4+1]*corr + p0*e.y + p1*f.y;
      acc[p*4+2] = acc[p*4+2]*corr + p0*e.z + p1*f.z;
      acc[p*4+3] = acc[p*4+3]*corr + p0*e.w + p1*f.w;
    }
    m = mn;
  }

  // ---- self-attend (targets only; counted once, by kg1)
  if (kg==1 && q >= 512){
    const float4* kp = (const float4*)&base[(size_t)q*768 + 256 + hoff];
    float s0=0.f,s1=0.f,s2=0.f,s3=0.f;
    #pragma unroll
    for (int p=0;p<8;p++){
      float4 t = kp[p];
      s0 += Q[p*4+0]*t.x; s1 += Q[p*4+1]*t.y;
      s2 += Q[p*4+2]*t.z; s3 += Q[p*4+3]*t.w;
    }
    float d0 = (s0+s1)+(s2+s3);
    float mn = fmaxf(m, d0);
    float corr = __expf(m-mn);
    float p0 = __expf(d0-mn);
    l = l*corr + p0;
    const float4* vp = (const float4*)&base[(size_t)q*768 + 512 + hoff];
    #pragma unroll
    for (int p=0;p<8;p++){
      float4 e = vp[p];
      acc[p*4+0]=acc[p*4+0]*corr + p0*e.x;
      acc[p*4+1]=acc[p*4+1]*corr + p0*e.y;
      acc[p*4+2]=acc[p*4+2]*corr + p0*e.z;
      acc[p*4+3]=acc[p*4+3]*corr + p0*e.w;
    }
    m = mn;
  }

  // ---- merge the two key-halves through LDS (reuse Ks; all reads done)
  __syncthreads();
  if (kg==1){
    float* pp = &Ks[(size_t)qi*36];
    #pragma unroll
    for (int d=0;d<32;d++) pp[d]=acc[d];
    pp[32]=m; pp[33]=l;
  }
  __syncthreads();
  if (kg==0){
    const float* pp = &Ks[(size_t)qi*36];
    float m2 = pp[32], l2 = pp[33];
    float mn = fmaxf(m, m2);
    float c1 = __expf(m-mn), c2 = __expf(m2-mn);
    float inv = 1.f/(l*c1 + l2*c2);
    float* op = o + ((size_t)b*1024 + q)*256 + hoff;
    #pragma unroll
    for (int p=0;p<8;p++){
      float4 t;
      t.x = (acc[p*4+0]*c1 + pp[p*4+0]*c2)*inv;
      t.y = (acc[p*4+1]*c1 + pp[p*4+1]*c2)*inv;
      t.z = (acc[p*4+2]*c1 + pp[p*4+2]*c2)*inv;
      t.w = (acc[p*4+3]*c1 + pp[p*4+3]*c2)*inv;
      *(float4*)&op[p*4] = t;
    }
  }
}

// ---------------------------------------------------------------- launch
extern "C" void kernel_launch(void* const* d_in, const int* in_sizes, int n_in,
                              void* d_out, int out_size, void* d_ws, size_t ws_size,
                              hipStream_t stream)
{
  (void)in_sizes; (void)n_in; (void)out_size;
  const float* xc   = (const float*)d_in[0];
  const float* yc   = (const float*)d_in[1];
  const float* xt   = (const float*)d_in[2];
  const float* eW1  = (const float*)d_in[3];
  const float* eb1  = (const float*)d_in[4];
  const float* eW2  = (const float*)d_in[5];
  const float* eb2  = (const float*)d_in[6];
  const float* Wqkv = (const float*)d_in[7];
  const float* bqkv = (const float*)d_in[8];
  const float* Wo   = (const float*)d_in[9];
  const float* bo   = (const float*)d_in[10];
  const float* ln1g = (const float*)d_in[11];
  const float* ln1b = (const float*)d_in[12];
  const float* ln2g = (const float*)d_in[13];
  const float* ln2b = (const float*)d_in[14];
  const float* Wff1 = (const float*)d_in[15];
  const float* bff1 = (const float*)d_in[16];
  const float* Wff2 = (const float*)d_in[17];
  const float* bff2 = (const float*)d_in[18];

  float* zf = (float*)d_out;            // residual stream [8][1024][256] f32 = 8 MB
  char* ws = (char*)d_ws;
  float* hb      = (float*)(ws);                        // 8 MB (LN out / attn out)
  float* scratch = (float*)(ws + (size_t)8*1024*1024);  // qkv / ffh

  const bool bigws = (ws_size == 0) || (ws_size >= (size_t)33*1024*1024);

  encoder_kernel<<<8192, 256, 0, stream>>>(xc, yc, xt, eW1, eb1, eW2, eb2, zf);

  for (int l=0; l<6; l++){
    const float* Wq = Wqkv + (size_t)l*256*768;
    const float* Wl = Wo   + (size_t)l*256*256;
    const float* W1 = Wff1 + (size_t)l*256*1024;
    const float* W2 = Wff2 + (size_t)l*1024*256;

    ln_fast<<<8192, 256, 0, stream>>>(zf, ln1g+l*256, ln1b+l*256, hb);
    if (bigws){
      // full-batch: qkv = 24 MB scratch
      gemm_v2<128,0><<<dim3(6,64), 256, 0, stream>>>(hb, Wq, bqkv+l*768,
                                                     nullptr, scratch, 768, 256);
      attn_v5<<<dim3(4,8,8), 512, 0, stream>>>(scratch, hb);   // hb consumed by gemm above
    } else {
      for (int c=0; c<4; c++){           // 2 batches per chunk (6 MB scratch)
        float* hrows = hb + (size_t)c*2048*256;
        gemm_v2<128,0><<<dim3(6,16), 256, 0, stream>>>(hrows, Wq, bqkv+l*768,
                                                       nullptr, scratch, 768, 256);
        attn_v5<<<dim3(4,8,2), 512, 0, stream>>>(scratch, hrows);
      }
    }
    gemm_v2<64,2><<<dim3(4,64), 256, 0, stream>>>(hb, Wl, bo+l*256, zf, zf, 256, 256);

    ln_fast<<<8192, 256, 0, stream>>>(zf, ln2g+l*256, ln2b+l*256, hb);
    if (bigws){
      for (int c=0; c<2; c++){           // 4-batch FF chunks (ffh 16 MB scratch)
        float* hrows = hb + (size_t)c*4096*256;
        float* zrows = zf + (size_t)c*4096*256;
        gemm_v2<128,1><<<dim3(8,32), 256, 0, stream>>>(hrows, W1, bff1+l*1024,
                                                       nullptr, scratch, 1024, 256);
        gemm_v2<64,2><<<dim3(4,32), 256, 0, stream>>>(scratch, W2, bff2+l*256,
                                                      zrows, zrows, 256, 1024);
      }
    } else {
      for (int c=0; c<4; c++){           // 2-batch FF chunks (ffh 8 MB scratch)
        float* hrows = hb + (size_t)c*2048*256;
        float* zrows = zf + (size_t)c*2048*256;
        gemm_v2<128,1><<<dim3(8,16), 256, 0, stream>>>(hrows, W1, bff1+l*1024,
                                                       nullptr, scratch, 1024, 256);
        gemm_v2<64,2><<<dim3(4,16), 256, 0, stream>>>(scratch, W2, bff2+l*256,
                                                      zrows, zrows, 256, 1024);
      }
    }
  }
}

// Round 5
// 5487.370 us; speedup vs baseline: 3.1161x; 3.1161x over previous
//
#include <hip/hip_runtime.h>

// ---------------------------------------------------------------- encoder
__global__ __launch_bounds__(256) void encoder_kernel(
    const float* __restrict__ xc, const float* __restrict__ yc, const float* __restrict__ xt,
    const float* __restrict__ W1, const float* __restrict__ b1,
    const float* __restrict__ W2, const float* __restrict__ b2,
    float* __restrict__ z)
{
  __shared__ float zin[10];
  __shared__ float hid[256];
  int blk = blockIdx.x; int b = blk>>10; int t = blk & 1023;
  int tid = threadIdx.x;
  if (tid < 10){
    float v;
    if (tid < 8)      v = (t<512) ? xc[((size_t)b*512+t)*8+tid] : xt[((size_t)b*512+(t-512))*8+tid];
    else if (tid==8)  v = (t<512) ? yc[(size_t)b*512+t] : 0.f;
    else              v = (t<512) ? 0.f : 1.f;
    zin[tid]=v;
  }
  __syncthreads();
  float s = b1[tid];
  #pragma unroll
  for (int i=0;i<10;i++) s += zin[i]*W1[i*256+tid];
  hid[tid] = fmaxf(s, 0.f);
  __syncthreads();
  float o = b2[tid];
  for (int j=0;j<256;j++) o += hid[j]*W2[j*256+tid];
  z[((size_t)b*1024+t)*256 + tid] = o;
}

// ---------------------------------------------------------------- layernorm
__global__ __launch_bounds__(256) void ln_fast(const float* __restrict__ z,
    const float* __restrict__ g, const float* __restrict__ be, float* __restrict__ h)
{
  __shared__ float red[256];
  int row = blockIdx.x, tid = threadIdx.x;
  float x = z[(size_t)row*256 + tid];
  red[tid] = x; __syncthreads();
  for (int s=128; s>0; s>>=1){ if (tid<s) red[tid]+=red[tid+s]; __syncthreads(); }
  float mu = red[0] * (1.f/256.f); __syncthreads();
  float d = x - mu;
  red[tid] = d*d; __syncthreads();
  for (int s=128; s>0; s>>=1){ if (tid<s) red[tid]+=red[tid+s]; __syncthreads(); }
  float var = red[0] * (1.f/256.f);
  float r = rsqrtf(var + 1e-5f);
  h[(size_t)row*256+tid] = d*r*g[tid] + be[tid];
}

// ---------------------------------------------------------------- gemm_v2
// out[M x N] = EPI(A[M x K] @ B[K x N] + bias)
// EPI 0: plain ; 1: relu ; 2: + resid (out may alias resid)
// BM=128 fixed, BN in {128,64}, micro-tile 8x(BN/16), BK=16, 256 threads.
// Register-prefetch double-buffered LDS: ONE barrier per K-tile,
// 64 FMA per 4 ds_read_b128. Lane map: wave = 8x8 lane grid so A/B LDS reads
// alias <=2-way (free). Requires M%128==0, N%BN==0, K%16==0.
// launch_bounds(256,2): VGPR cap 256. Round-4 lesson: (256,4) capped VGPRs
// at 64 -> accumulator spill to scratch -> 1 GB/dispatch HBM write traffic,
// 31 ms dispatches. Never bound occupancy below the micro-tile's register need.
template<int BN, int EPI>
__global__ __launch_bounds__(256, 2) void gemm_v2(
    const float* __restrict__ A, const float* __restrict__ B,
    const float* __restrict__ bias, const float* __restrict__ resid,
    float* __restrict__ out, int N, int K)
{
  constexpr int BM = 128, BK = 16;
  constexpr int TN = BN/16;            // 8 or 4
  constexpr int LDA = BM + 4;          // 132: k-stride stays 16B-aligned
  constexpr int LDB = BN + 4;          // 132 / 68: both 16B-aligned strides
  __shared__ float As[2][BK*LDA];
  __shared__ float Bs[2][BK*LDB];

  const int tid = threadIdx.x;
  const int wv = tid >> 6, ln = tid & 63;
  const int trow = ((wv>>1)<<3) + (ln>>3);   // 0..15 (8 rows each)
  const int tcol = ((wv&1)<<3) + (ln&7);     // 0..15 (TN cols each)
  const int m0 = blockIdx.y*BM, n0 = blockIdx.x*BN;

  // A stage: thread loads rows (ar, ar+64), cols ac..ac+3 of the 128x16 slab
  const int ar = tid>>2, ac = (tid&3)<<2;
  // B stage: BN=128: rows (br, br+8), 2 float4; BN=64: row br, 1 float4
  const int br = (BN==128) ? (tid>>5) : (tid>>4);
  const int bc = (BN==128) ? ((tid&31)<<2) : ((tid&15)<<2);

  const float* Ap = &A[(size_t)(m0+ar)*K + ac];
  const float* Bp = &B[(size_t)br*N + n0 + bc];

  float4 pa0, pa1, pb0, pb1;
  pa0 = *(const float4*)&Ap[0];
  pa1 = *(const float4*)&Ap[(size_t)64*K];
  pb0 = *(const float4*)&Bp[0];
  if (BN==128) pb1 = *(const float4*)&Bp[(size_t)8*N];

  {
    float* as = As[0]; float* bs = Bs[0];
    as[(ac+0)*LDA+ar]    = pa0.x; as[(ac+1)*LDA+ar]    = pa0.y;
    as[(ac+2)*LDA+ar]    = pa0.z; as[(ac+3)*LDA+ar]    = pa0.w;
    as[(ac+0)*LDA+ar+64] = pa1.x; as[(ac+1)*LDA+ar+64] = pa1.y;
    as[(ac+2)*LDA+ar+64] = pa1.z; as[(ac+3)*LDA+ar+64] = pa1.w;
    *(float4*)&bs[br*LDB+bc] = pb0;
    if (BN==128) *(float4*)&bs[(br+8)*LDB+bc] = pb1;
  }
  __syncthreads();

  float acc[8][TN] = {};
  const int NT = K/BK;
  int cur = 0;
  for (int t=0; t<NT; ++t){
    if (t+1 < NT){
      const float* Ap2 = Ap + (t+1)*BK;
      pa0 = *(const float4*)&Ap2[0];
      pa1 = *(const float4*)&Ap2[(size_t)64*K];
      const float* Bp2 = Bp + (size_t)(t+1)*BK*N;
      pb0 = *(const float4*)&Bp2[0];
      if (BN==128) pb1 = *(const float4*)&Bp2[(size_t)8*N];
    }
    const float* as = As[cur]; const float* bs = Bs[cur];
    #pragma unroll
    for (int k=0;k<BK;k++){
      float4 x0 = *(const float4*)&as[k*LDA + trow*8];
      float4 x1 = *(const float4*)&as[k*LDA + trow*8 + 4];
      float av[8] = {x0.x,x0.y,x0.z,x0.w, x1.x,x1.y,x1.z,x1.w};
      float bv[TN];
      {
        float4 y0 = *(const float4*)&bs[k*LDB + tcol*TN];
        bv[0]=y0.x; bv[1]=y0.y; bv[2]=y0.z; bv[3]=y0.w;
        if (BN==128){
          float4 y1 = *(const float4*)&bs[k*LDB + tcol*TN + 4];
          bv[4]=y1.x; bv[5]=y1.y; bv[6]=y1.z; bv[7]=y1.w;
        }
      }
      #pragma unroll
      for (int i=0;i<8;i++)
        #pragma unroll
        for (int j=0;j<TN;j++)
          acc[i][j] += av[i]*bv[j];
    }
    if (t+1 < NT){
      float* as2 = As[cur^1]; float* bs2 = Bs[cur^1];
      as2[(ac+0)*LDA+ar]    = pa0.x; as2[(ac+1)*LDA+ar]    = pa0.y;
      as2[(ac+2)*LDA+ar]    = pa0.z; as2[(ac+3)*LDA+ar]    = pa0.w;
      as2[(ac+0)*LDA+ar+64] = pa1.x; as2[(ac+1)*LDA+ar+64] = pa1.y;
      as2[(ac+2)*LDA+ar+64] = pa1.z; as2[(ac+3)*LDA+ar+64] = pa1.w;
      *(float4*)&bs2[br*LDB+bc] = pb0;
      if (BN==128) *(float4*)&bs2[(br+8)*LDB+bc] = pb1;
    }
    __syncthreads();
    cur ^= 1;
  }

  // epilogue
  #pragma unroll
  for (int j4=0; j4<TN/4; ++j4){
    const int gc0 = n0 + tcol*TN + j4*4;
    float4 bsv = *(const float4*)&bias[gc0];
    float bb[4] = {bsv.x,bsv.y,bsv.z,bsv.w};
    #pragma unroll
    for (int i=0;i<8;i++){
      int gr = m0 + trow*8 + i;
      size_t off = (size_t)gr*N + gc0;
      float v0=acc[i][j4*4+0]+bb[0], v1=acc[i][j4*4+1]+bb[1];
      float v2=acc[i][j4*4+2]+bb[2], v3=acc[i][j4*4+3]+bb[3];
      if (EPI==1){ v0=fmaxf(v0,0.f); v1=fmaxf(v1,0.f); v2=fmaxf(v2,0.f); v3=fmaxf(v3,0.f); }
      if (EPI==2){ float4 rv = *(const float4*)&resid[off]; v0+=rv.x; v1+=rv.y; v2+=rv.z; v3+=rv.w; }
      float4 o; o.x=v0; o.y=v1; o.z=v2; o.w=v3;
      *(float4*)&out[off] = o;
    }
  }
}

// ---------------------------------------------------------------- attention v5
// One thread = one full (q,h) row; Q[32] and acc[32] in registers.
// Whole K/V head-slice (512 keys x 32 dims x 2) staged once in LDS (128 KB).
// All lanes of a wave process the same key in lockstep -> every LDS read is a
// same-address broadcast (conflict-free); the 32-dot is entirely in-lane:
// ZERO cross-lane ops and ZERO global loads in the inner loop.
// Block = 512 threads: tid<256 -> keys 0..255 (kg0), tid>=256 -> keys 256..511
// (kg1), same 256 q-rows; the two online-softmax halves merge through LDS.
// Grid = (4 qgroups, 8 h, 8 b) = 256 blocks = 1 block/CU (2 waves/SIMD).
// Targets (q>=512 <=> qg>=2) self-attend; handled once by kg1.
__global__ __launch_bounds__(512, 2) void attn_v5(
    const float* __restrict__ qkv, float* __restrict__ o)
{
  __shared__ float Ks[512*32];   // 64 KB
  __shared__ float Vs[512*32];   // 64 KB
  const int tid = threadIdx.x;
  const int qg = blockIdx.x, h = blockIdx.y, b = blockIdx.z;
  const int qi = tid & 255;
  const int kg = tid >> 8;             // 0: keys 0..255, 1: keys 256..511
  const int q  = qg*256 + qi;
  const float* base = qkv + (size_t)b*1024*768;
  const int hoff = h*32;
  const float sc = 0.17677669529663687f;   // 1/sqrt(32)

  // ---- stage K,V (all 512 keys) into LDS, coalesced (8 lanes x 16B per row)
  #pragma unroll
  for (int t = 0; t < 8; ++t){
    int i = tid + t*512;               // 0..4095
    int row = i >> 3, c4 = (i & 7)*4;
    *(float4*)&Ks[row*32 + c4] = *(const float4*)&base[(size_t)row*768 + 256 + hoff + c4];
  }
  #pragma unroll
  for (int t = 0; t < 8; ++t){
    int i = tid + t*512;
    int row = i >> 3, c4 = (i & 7)*4;
    *(float4*)&Vs[row*32 + c4] = *(const float4*)&base[(size_t)row*768 + 512 + hoff + c4];
  }

  // ---- load Q (scaled)
  float Q[32];
  {
    const float4* qp = (const float4*)&base[(size_t)q*768 + hoff];
    #pragma unroll
    for (int p=0;p<8;p++){
      float4 t = qp[p];
      Q[p*4+0]=t.x*sc; Q[p*4+1]=t.y*sc; Q[p*4+2]=t.z*sc; Q[p*4+3]=t.w*sc;
    }
  }
  __syncthreads();

  float m = -1e30f, l = 0.f;
  float acc[32];
  #pragma unroll
  for (int d=0;d<32;d++) acc[d]=0.f;

  const int j0 = kg*256;
  for (int jj=0; jj<256; jj+=2){
    const float* k0 = &Ks[(j0+jj)*32];
    const float* k1 = &Ks[(j0+jj+1)*32];
    float s00=0.f,s01=0.f,s02=0.f,s03=0.f, s10=0.f,s11=0.f,s12=0.f,s13=0.f;
    #pragma unroll
    for (int p=0;p<8;p++){
      float4 a = *(const float4*)&k0[p*4];
      float4 c = *(const float4*)&k1[p*4];
      s00 += Q[p*4+0]*a.x; s01 += Q[p*4+1]*a.y;
      s02 += Q[p*4+2]*a.z; s03 += Q[p*4+3]*a.w;
      s10 += Q[p*4+0]*c.x; s11 += Q[p*4+1]*c.y;
      s12 += Q[p*4+2]*c.z; s13 += Q[p*4+3]*c.w;
    }
    float d0 = (s00+s01)+(s02+s03);
    float d1 = (s10+s11)+(s12+s13);
    float mn = fmaxf(m, fmaxf(d0,d1));
    float corr = __expf(m-mn);
    float p0 = __expf(d0-mn), p1 = __expf(d1-mn);
    l = l*corr + p0 + p1;
    const float* v0 = &Vs[(j0+jj)*32];
    const float* v1 = &Vs[(j0+jj+1)*32];
    #pragma unroll
    for (int p=0;p<8;p++){
      float4 e = *(const float4*)&v0[p*4];
      float4 f = *(const float4*)&v1[p*4];
      acc[p*4+0] = acc[p*4+0]*corr + p0*e.x + p1*f.x;
      acc[p*4+1] = acc[p*4+1]*corr + p0*e.y + p1*f.y;
      acc[p*4+2] = acc[p*4+2]*corr + p0*e.z + p1*f.z;
      acc[p*4+3] = acc[p*4+3]*corr + p0*e.w + p1*f.w;
    }
    m = mn;
  }

  // ---- self-attend (targets only; counted once, by kg1)
  if (kg==1 && q >= 512){
    const float4* kp = (const float4*)&base[(size_t)q*768 + 256 + hoff];
    float s0=0.f,s1=0.f,s2=0.f,s3=0.f;
    #pragma unroll
    for (int p=0;p<8;p++){
      float4 t = kp[p];
      s0 += Q[p*4+0]*t.x; s1 += Q[p*4+1]*t.y;
      s2 += Q[p*4+2]*t.z; s3 += Q[p*4+3]*t.w;
    }
    float d0 = (s0+s1)+(s2+s3);
    float mn = fmaxf(m, d0);
    float corr = __expf(m-mn);
    float p0 = __expf(d0-mn);
    l = l*corr + p0;
    const float4* vp = (const float4*)&base[(size_t)q*768 + 512 + hoff];
    #pragma unroll
    for (int p=0;p<8;p++){
      float4 e = vp[p];
      acc[p*4+0]=acc[p*4+0]*corr + p0*e.x;
      acc[p*4+1]=acc[p*4+1]*corr + p0*e.y;
      acc[p*4+2]=acc[p*4+2]*corr + p0*e.z;
      acc[p*4+3]=acc[p*4+3]*corr + p0*e.w;
    }
    m = mn;
  }

  // ---- merge the two key-halves through LDS (reuse Ks; all reads done)
  __syncthreads();
  if (kg==1){
    float* pp = &Ks[(size_t)qi*36];
    #pragma unroll
    for (int d=0;d<32;d++) pp[d]=acc[d];
    pp[32]=m; pp[33]=l;
  }
  __syncthreads();
  if (kg==0){
    const float* pp = &Ks[(size_t)qi*36];
    float m2 = pp[32], l2 = pp[33];
    float mn = fmaxf(m, m2);
    float c1 = __expf(m-mn), c2 = __expf(m2-mn);
    float inv = 1.f/(l*c1 + l2*c2);
    float* op = o + ((size_t)b*1024 + q)*256 + hoff;
    #pragma unroll
    for (int p=0;p<8;p++){
      float4 t;
      t.x = (acc[p*4+0]*c1 + pp[p*4+0]*c2)*inv;
      t.y = (acc[p*4+1]*c1 + pp[p*4+1]*c2)*inv;
      t.z = (acc[p*4+2]*c1 + pp[p*4+2]*c2)*inv;
      t.w = (acc[p*4+3]*c1 + pp[p*4+3]*c2)*inv;
      *(float4*)&op[p*4] = t;
    }
  }
}

// ---------------------------------------------------------------- launch
extern "C" void kernel_launch(void* const* d_in, const int* in_sizes, int n_in,
                              void* d_out, int out_size, void* d_ws, size_t ws_size,
                              hipStream_t stream)
{
  (void)in_sizes; (void)n_in; (void)out_size;
  const float* xc   = (const float*)d_in[0];
  const float* yc   = (const float*)d_in[1];
  const float* xt   = (const float*)d_in[2];
  const float* eW1  = (const float*)d_in[3];
  const float* eb1  = (const float*)d_in[4];
  const float* eW2  = (const float*)d_in[5];
  const float* eb2  = (const float*)d_in[6];
  const float* Wqkv = (const float*)d_in[7];
  const float* bqkv = (const float*)d_in[8];
  const float* Wo   = (const float*)d_in[9];
  const float* bo   = (const float*)d_in[10];
  const float* ln1g = (const float*)d_in[11];
  const float* ln1b = (const float*)d_in[12];
  const float* ln2g = (const float*)d_in[13];
  const float* ln2b = (const float*)d_in[14];
  const float* Wff1 = (const float*)d_in[15];
  const float* bff1 = (const float*)d_in[16];
  const float* Wff2 = (const float*)d_in[17];
  const float* bff2 = (const float*)d_in[18];

  float* zf = (float*)d_out;            // residual stream [8][1024][256] f32 = 8 MB
  char* ws = (char*)d_ws;
  float* hb      = (float*)(ws);                        // 8 MB (LN out / attn out)
  float* scratch = (float*)(ws + (size_t)8*1024*1024);  // qkv / ffh

  const bool bigws = (ws_size == 0) || (ws_size >= (size_t)33*1024*1024);

  encoder_kernel<<<8192, 256, 0, stream>>>(xc, yc, xt, eW1, eb1, eW2, eb2, zf);

  for (int l=0; l<6; l++){
    const float* Wq = Wqkv + (size_t)l*256*768;
    const float* Wl = Wo   + (size_t)l*256*256;
    const float* W1 = Wff1 + (size_t)l*256*1024;
    const float* W2 = Wff2 + (size_t)l*1024*256;

    ln_fast<<<8192, 256, 0, stream>>>(zf, ln1g+l*256, ln1b+l*256, hb);
    if (bigws){
      // full-batch: qkv = 24 MB scratch
      gemm_v2<128,0><<<dim3(6,64), 256, 0, stream>>>(hb, Wq, bqkv+l*768,
                                                     nullptr, scratch, 768, 256);
      attn_v5<<<dim3(4,8,8), 512, 0, stream>>>(scratch, hb);   // hb consumed by gemm above
    } else {
      for (int c=0; c<4; c++){           // 2 batches per chunk (6 MB scratch)
        float* hrows = hb + (size_t)c*2048*256;
        gemm_v2<128,0><<<dim3(6,16), 256, 0, stream>>>(hrows, Wq, bqkv+l*768,
                                                       nullptr, scratch, 768, 256);
        attn_v5<<<dim3(4,8,2), 512, 0, stream>>>(scratch, hrows);
      }
    }
    gemm_v2<64,2><<<dim3(4,64), 256, 0, stream>>>(hb, Wl, bo+l*256, zf, zf, 256, 256);

    ln_fast<<<8192, 256, 0, stream>>>(zf, ln2g+l*256, ln2b+l*256, hb);
    if (bigws){
      for (int c=0; c<2; c++){           // 4-batch FF chunks (ffh 16 MB scratch)
        float* hrows = hb + (size_t)c*4096*256;
        float* zrows = zf + (size_t)c*4096*256;
        gemm_v2<128,1><<<dim3(8,32), 256, 0, stream>>>(hrows, W1, bff1+l*1024,
                                                       nullptr, scratch, 1024, 256);
        gemm_v2<64,2><<<dim3(4,32), 256, 0, stream>>>(scratch, W2, bff2+l*256,
                                                      zrows, zrows, 256, 1024);
      }
    } else {
      for (int c=0; c<4; c++){           // 2-batch FF chunks (ffh 8 MB scratch)
        float* hrows = hb + (size_t)c*2048*256;
        float* zrows = zf + (size_t)c*2048*256;
        gemm_v2<128,1><<<dim3(8,16), 256, 0, stream>>>(hrows, W1, bff1+l*1024,
                                                       nullptr, scratch, 1024, 256);
        gemm_v2<64,2><<<dim3(4,16), 256, 0, stream>>>(scratch, W2, bff2+l*256,
                                                      zrows, zrows, 256, 1024);
      }
    }
  }
}

// Round 6
// 2749.184 us; speedup vs baseline: 6.2198x; 1.9960x over previous
//
#include <hip/hip_runtime.h>

// ---------------------------------------------------------------- encoder
__global__ __launch_bounds__(256) void encoder_kernel(
    const float* __restrict__ xc, const float* __restrict__ yc, const float* __restrict__ xt,
    const float* __restrict__ W1, const float* __restrict__ b1,
    const float* __restrict__ W2, const float* __restrict__ b2,
    float* __restrict__ z)
{
  __shared__ float zin[10];
  __shared__ float hid[256];
  int blk = blockIdx.x; int b = blk>>10; int t = blk & 1023;
  int tid = threadIdx.x;
  if (tid < 10){
    float v;
    if (tid < 8)      v = (t<512) ? xc[((size_t)b*512+t)*8+tid] : xt[((size_t)b*512+(t-512))*8+tid];
    else if (tid==8)  v = (t<512) ? yc[(size_t)b*512+t] : 0.f;
    else              v = (t<512) ? 0.f : 1.f;
    zin[tid]=v;
  }
  __syncthreads();
  float s = b1[tid];
  #pragma unroll
  for (int i=0;i<10;i++) s += zin[i]*W1[i*256+tid];
  hid[tid] = fmaxf(s, 0.f);
  __syncthreads();
  float o = b2[tid];
  for (int j=0;j<256;j++) o += hid[j]*W2[j*256+tid];
  z[((size_t)b*1024+t)*256 + tid] = o;
}

// ---------------------------------------------------------------- layernorm
__global__ __launch_bounds__(256) void ln_fast(const float* __restrict__ z,
    const float* __restrict__ g, const float* __restrict__ be, float* __restrict__ h)
{
  __shared__ float red[256];
  int row = blockIdx.x, tid = threadIdx.x;
  float x = z[(size_t)row*256 + tid];
  red[tid] = x; __syncthreads();
  for (int s=128; s>0; s>>=1){ if (tid<s) red[tid]+=red[tid+s]; __syncthreads(); }
  float mu = red[0] * (1.f/256.f); __syncthreads();
  float d = x - mu;
  red[tid] = d*d; __syncthreads();
  for (int s=128; s>0; s>>=1){ if (tid<s) red[tid]+=red[tid+s]; __syncthreads(); }
  float var = red[0] * (1.f/256.f);
  float r = rsqrtf(var + 1e-5f);
  h[(size_t)row*256+tid] = d*r*g[tid] + be[tid];
}

// ---------------------------------------------------------------- gemm_v2
// out[M x N] = EPI(A[M x K] @ B[K x N] + bias)
// EPI 0: plain ; 1: relu ; 2: + resid (out may alias resid)
// BM=128 fixed, BN in {128,64}, micro-tile 8x(BN/16), BK=16, 256 threads.
// Register-prefetch double-buffered LDS: ONE barrier per K-tile,
// 64 FMA per 4 ds_read_b128. Lane map: wave = 8x8 lane grid so A/B LDS reads
// alias <=2-way (free). Requires M%128==0, N%BN==0, K%16==0.
// NO min-waves in launch_bounds: on this compiler __launch_bounds__(256,W)
// caps VGPRs at 256/W -> (256,4)=64 and (256,2)=128 both spilled the ~140-VGPR
// micro-tile to scratch (674 MB HBM writes/dispatch, 31ms/255us dispatches).
// Unconstrained, the allocator takes ~140 VGPR -> ~3 waves/SIMD, no spill.
template<int BN, int EPI>
__global__ __launch_bounds__(256) void gemm_v2(
    const float* __restrict__ A, const float* __restrict__ B,
    const float* __restrict__ bias, const float* __restrict__ resid,
    float* __restrict__ out, int N, int K)
{
  constexpr int BM = 128, BK = 16;
  constexpr int TN = BN/16;            // 8 or 4
  constexpr int LDA = BM + 4;          // 132: k-stride stays 16B-aligned
  constexpr int LDB = BN + 4;          // 132 / 68: both 16B-aligned strides
  __shared__ float As[2][BK*LDA];
  __shared__ float Bs[2][BK*LDB];

  const int tid = threadIdx.x;
  const int wv = tid >> 6, ln = tid & 63;
  const int trow = ((wv>>1)<<3) + (ln>>3);   // 0..15 (8 rows each)
  const int tcol = ((wv&1)<<3) + (ln&7);     // 0..15 (TN cols each)
  const int m0 = blockIdx.y*BM, n0 = blockIdx.x*BN;

  // A stage: thread loads rows (ar, ar+64), cols ac..ac+3 of the 128x16 slab
  const int ar = tid>>2, ac = (tid&3)<<2;
  // B stage: BN=128: rows (br, br+8), 2 float4; BN=64: row br, 1 float4
  const int br = (BN==128) ? (tid>>5) : (tid>>4);
  const int bc = (BN==128) ? ((tid&31)<<2) : ((tid&15)<<2);

  const float* Ap = &A[(size_t)(m0+ar)*K + ac];
  const float* Bp = &B[(size_t)br*N + n0 + bc];

  float4 pa0, pa1, pb0, pb1;
  pa0 = *(const float4*)&Ap[0];
  pa1 = *(const float4*)&Ap[(size_t)64*K];
  pb0 = *(const float4*)&Bp[0];
  if (BN==128) pb1 = *(const float4*)&Bp[(size_t)8*N];

  {
    float* as = As[0]; float* bs = Bs[0];
    as[(ac+0)*LDA+ar]    = pa0.x; as[(ac+1)*LDA+ar]    = pa0.y;
    as[(ac+2)*LDA+ar]    = pa0.z; as[(ac+3)*LDA+ar]    = pa0.w;
    as[(ac+0)*LDA+ar+64] = pa1.x; as[(ac+1)*LDA+ar+64] = pa1.y;
    as[(ac+2)*LDA+ar+64] = pa1.z; as[(ac+3)*LDA+ar+64] = pa1.w;
    *(float4*)&bs[br*LDB+bc] = pb0;
    if (BN==128) *(float4*)&bs[(br+8)*LDB+bc] = pb1;
  }
  __syncthreads();

  float acc[8][TN] = {};
  const int NT = K/BK;
  int cur = 0;
  for (int t=0; t<NT; ++t){
    if (t+1 < NT){
      const float* Ap2 = Ap + (t+1)*BK;
      pa0 = *(const float4*)&Ap2[0];
      pa1 = *(const float4*)&Ap2[(size_t)64*K];
      const float* Bp2 = Bp + (size_t)(t+1)*BK*N;
      pb0 = *(const float4*)&Bp2[0];
      if (BN==128) pb1 = *(const float4*)&Bp2[(size_t)8*N];
    }
    const float* as = As[cur]; const float* bs = Bs[cur];
    #pragma unroll
    for (int k=0;k<BK;k++){
      float4 x0 = *(const float4*)&as[k*LDA + trow*8];
      float4 x1 = *(const float4*)&as[k*LDA + trow*8 + 4];
      float av[8] = {x0.x,x0.y,x0.z,x0.w, x1.x,x1.y,x1.z,x1.w};
      float bv[TN];
      {
        float4 y0 = *(const float4*)&bs[k*LDB + tcol*TN];
        bv[0]=y0.x; bv[1]=y0.y; bv[2]=y0.z; bv[3]=y0.w;
        if (BN==128){
          float4 y1 = *(const float4*)&bs[k*LDB + tcol*TN + 4];
          bv[4]=y1.x; bv[5]=y1.y; bv[6]=y1.z; bv[7]=y1.w;
        }
      }
      #pragma unroll
      for (int i=0;i<8;i++)
        #pragma unroll
        for (int j=0;j<TN;j++)
          acc[i][j] += av[i]*bv[j];
    }
    if (t+1 < NT){
      float* as2 = As[cur^1]; float* bs2 = Bs[cur^1];
      as2[(ac+0)*LDA+ar]    = pa0.x; as2[(ac+1)*LDA+ar]    = pa0.y;
      as2[(ac+2)*LDA+ar]    = pa0.z; as2[(ac+3)*LDA+ar]    = pa0.w;
      as2[(ac+0)*LDA+ar+64] = pa1.x; as2[(ac+1)*LDA+ar+64] = pa1.y;
      as2[(ac+2)*LDA+ar+64] = pa1.z; as2[(ac+3)*LDA+ar+64] = pa1.w;
      *(float4*)&bs2[br*LDB+bc] = pb0;
      if (BN==128) *(float4*)&bs2[(br+8)*LDB+bc] = pb1;
    }
    __syncthreads();
    cur ^= 1;
  }

  // epilogue
  #pragma unroll
  for (int j4=0; j4<TN/4; ++j4){
    const int gc0 = n0 + tcol*TN + j4*4;
    float4 bsv = *(const float4*)&bias[gc0];
    float bb[4] = {bsv.x,bsv.y,bsv.z,bsv.w};
    #pragma unroll
    for (int i=0;i<8;i++){
      int gr = m0 + trow*8 + i;
      size_t off = (size_t)gr*N + gc0;
      float v0=acc[i][j4*4+0]+bb[0], v1=acc[i][j4*4+1]+bb[1];
      float v2=acc[i][j4*4+2]+bb[2], v3=acc[i][j4*4+3]+bb[3];
      if (EPI==1){ v0=fmaxf(v0,0.f); v1=fmaxf(v1,0.f); v2=fmaxf(v2,0.f); v3=fmaxf(v3,0.f); }
      if (EPI==2){ float4 rv = *(const float4*)&resid[off]; v0+=rv.x; v1+=rv.y; v2+=rv.z; v3+=rv.w; }
      float4 o; o.x=v0; o.y=v1; o.z=v2; o.w=v3;
      *(float4*)&out[off] = o;
    }
  }
}

// ---------------------------------------------------------------- attention v5
// One thread = one full (q,h) row; Q[32] and acc[32] in registers.
// Whole K/V head-slice (512 keys x 32 dims x 2) staged once in LDS (128 KB).
// All lanes of a wave process the same key in lockstep -> every LDS read is a
// same-address broadcast (conflict-free); the 32-dot is entirely in-lane:
// ZERO cross-lane ops and ZERO global loads in the inner loop.
// Block = 512 threads: tid<256 -> keys 0..255 (kg0), tid>=256 -> keys 256..511
// (kg1), same 256 q-rows; the two online-softmax halves merge through LDS.
// Grid = (4 qgroups, 8 h, 8 b) = 256 blocks = 1 block/CU (2 waves/SIMD).
// Targets (q>=512 <=> qg>=2) self-attend; handled once by kg1.
__global__ __launch_bounds__(512, 2) void attn_v5(
    const float* __restrict__ qkv, float* __restrict__ o)
{
  __shared__ float Ks[512*32];   // 64 KB
  __shared__ float Vs[512*32];   // 64 KB
  const int tid = threadIdx.x;
  const int qg = blockIdx.x, h = blockIdx.y, b = blockIdx.z;
  const int qi = tid & 255;
  const int kg = tid >> 8;             // 0: keys 0..255, 1: keys 256..511
  const int q  = qg*256 + qi;
  const float* base = qkv + (size_t)b*1024*768;
  const int hoff = h*32;
  const float sc = 0.17677669529663687f;   // 1/sqrt(32)

  // ---- stage K,V (all 512 keys) into LDS, coalesced (8 lanes x 16B per row)
  #pragma unroll
  for (int t = 0; t < 8; ++t){
    int i = tid + t*512;               // 0..4095
    int row = i >> 3, c4 = (i & 7)*4;
    *(float4*)&Ks[row*32 + c4] = *(const float4*)&base[(size_t)row*768 + 256 + hoff + c4];
  }
  #pragma unroll
  for (int t = 0; t < 8; ++t){
    int i = tid + t*512;
    int row = i >> 3, c4 = (i & 7)*4;
    *(float4*)&Vs[row*32 + c4] = *(const float4*)&base[(size_t)row*768 + 512 + hoff + c4];
  }

  // ---- load Q (scaled)
  float Q[32];
  {
    const float4* qp = (const float4*)&base[(size_t)q*768 + hoff];
    #pragma unroll
    for (int p=0;p<8;p++){
      float4 t = qp[p];
      Q[p*4+0]=t.x*sc; Q[p*4+1]=t.y*sc; Q[p*4+2]=t.z*sc; Q[p*4+3]=t.w*sc;
    }
  }
  __syncthreads();

  float m = -1e30f, l = 0.f;
  float acc[32];
  #pragma unroll
  for (int d=0;d<32;d++) acc[d]=0.f;

  const int j0 = kg*256;
  for (int jj=0; jj<256; jj+=2){
    const float* k0 = &Ks[(j0+jj)*32];
    const float* k1 = &Ks[(j0+jj+1)*32];
    float s00=0.f,s01=0.f,s02=0.f,s03=0.f, s10=0.f,s11=0.f,s12=0.f,s13=0.f;
    #pragma unroll
    for (int p=0;p<8;p++){
      float4 a = *(const float4*)&k0[p*4];
      float4 c = *(const float4*)&k1[p*4];
      s00 += Q[p*4+0]*a.x; s01 += Q[p*4+1]*a.y;
      s02 += Q[p*4+2]*a.z; s03 += Q[p*4+3]*a.w;
      s10 += Q[p*4+0]*c.x; s11 += Q[p*4+1]*c.y;
      s12 += Q[p*4+2]*c.z; s13 += Q[p*4+3]*c.w;
    }
    float d0 = (s00+s01)+(s02+s03);
    float d1 = (s10+s11)+(s12+s13);
    float mn = fmaxf(m, fmaxf(d0,d1));
    float corr = __expf(m-mn);
    float p0 = __expf(d0-mn), p1 = __expf(d1-mn);
    l = l*corr + p0 + p1;
    const float* v0 = &Vs[(j0+jj)*32];
    const float* v1 = &Vs[(j0+jj+1)*32];
    #pragma unroll
    for (int p=0;p<8;p++){
      float4 e = *(const float4*)&v0[p*4];
      float4 f = *(const float4*)&v1[p*4];
      acc[p*4+0] = acc[p*4+0]*corr + p0*e.x + p1*f.x;
      acc[p*4+1] = acc[p*4+1]*corr + p0*e.y + p1*f.y;
      acc[p*4+2] = acc[p*4+2]*corr + p0*e.z + p1*f.z;
      acc[p*4+3] = acc[p*4+3]*corr + p0*e.w + p1*f.w;
    }
    m = mn;
  }

  // ---- self-attend (targets only; counted once, by kg1)
  if (kg==1 && q >= 512){
    const float4* kp = (const float4*)&base[(size_t)q*768 + 256 + hoff];
    float s0=0.f,s1=0.f,s2=0.f,s3=0.f;
    #pragma unroll
    for (int p=0;p<8;p++){
      float4 t = kp[p];
      s0 += Q[p*4+0]*t.x; s1 += Q[p*4+1]*t.y;
      s2 += Q[p*4+2]*t.z; s3 += Q[p*4+3]*t.w;
    }
    float d0 = (s0+s1)+(s2+s3);
    float mn = fmaxf(m, d0);
    float corr = __expf(m-mn);
    float p0 = __expf(d0-mn);
    l = l*corr + p0;
    const float4* vp = (const float4*)&base[(size_t)q*768 + 512 + hoff];
    #pragma unroll
    for (int p=0;p<8;p++){
      float4 e = vp[p];
      acc[p*4+0]=acc[p*4+0]*corr + p0*e.x;
      acc[p*4+1]=acc[p*4+1]*corr + p0*e.y;
      acc[p*4+2]=acc[p*4+2]*corr + p0*e.z;
      acc[p*4+3]=acc[p*4+3]*corr + p0*e.w;
    }
    m = mn;
  }

  // ---- merge the two key-halves through LDS (reuse Ks; all reads done)
  __syncthreads();
  if (kg==1){
    float* pp = &Ks[(size_t)qi*36];
    #pragma unroll
    for (int d=0;d<32;d++) pp[d]=acc[d];
    pp[32]=m; pp[33]=l;
  }
  __syncthreads();
  if (kg==0){
    const float* pp = &Ks[(size_t)qi*36];
    float m2 = pp[32], l2 = pp[33];
    float mn = fmaxf(m, m2);
    float c1 = __expf(m-mn), c2 = __expf(m2-mn);
    float inv = 1.f/(l*c1 + l2*c2);
    float* op = o + ((size_t)b*1024 + q)*256 + hoff;
    #pragma unroll
    for (int p=0;p<8;p++){
      float4 t;
      t.x = (acc[p*4+0]*c1 + pp[p*4+0]*c2)*inv;
      t.y = (acc[p*4+1]*c1 + pp[p*4+1]*c2)*inv;
      t.z = (acc[p*4+2]*c1 + pp[p*4+2]*c2)*inv;
      t.w = (acc[p*4+3]*c1 + pp[p*4+3]*c2)*inv;
      *(float4*)&op[p*4] = t;
    }
  }
}

// ---------------------------------------------------------------- launch
extern "C" void kernel_launch(void* const* d_in, const int* in_sizes, int n_in,
                              void* d_out, int out_size, void* d_ws, size_t ws_size,
                              hipStream_t stream)
{
  (void)in_sizes; (void)n_in; (void)out_size;
  const float* xc   = (const float*)d_in[0];
  const float* yc   = (const float*)d_in[1];
  const float* xt   = (const float*)d_in[2];
  const float* eW1  = (const float*)d_in[3];
  const float* eb1  = (const float*)d_in[4];
  const float* eW2  = (const float*)d_in[5];
  const float* eb2  = (const float*)d_in[6];
  const float* Wqkv = (const float*)d_in[7];
  const float* bqkv = (const float*)d_in[8];
  const float* Wo   = (const float*)d_in[9];
  const float* bo   = (const float*)d_in[10];
  const float* ln1g = (const float*)d_in[11];
  const float* ln1b = (const float*)d_in[12];
  const float* ln2g = (const float*)d_in[13];
  const float* ln2b = (const float*)d_in[14];
  const float* Wff1 = (const float*)d_in[15];
  const float* bff1 = (const float*)d_in[16];
  const float* Wff2 = (const float*)d_in[17];
  const float* bff2 = (const float*)d_in[18];

  float* zf = (float*)d_out;            // residual stream [8][1024][256] f32 = 8 MB
  char* ws = (char*)d_ws;
  float* hb      = (float*)(ws);                        // 8 MB (LN out / attn out)
  float* scratch = (float*)(ws + (size_t)8*1024*1024);  // qkv / ffh

  const bool bigws = (ws_size == 0) || (ws_size >= (size_t)33*1024*1024);

  encoder_kernel<<<8192, 256, 0, stream>>>(xc, yc, xt, eW1, eb1, eW2, eb2, zf);

  for (int l=0; l<6; l++){
    const float* Wq = Wqkv + (size_t)l*256*768;
    const float* Wl = Wo   + (size_t)l*256*256;
    const float* W1 = Wff1 + (size_t)l*256*1024;
    const float* W2 = Wff2 + (size_t)l*1024*256;

    ln_fast<<<8192, 256, 0, stream>>>(zf, ln1g+l*256, ln1b+l*256, hb);
    if (bigws){
      // full-batch: qkv = 24 MB scratch
      gemm_v2<128,0><<<dim3(6,64), 256, 0, stream>>>(hb, Wq, bqkv+l*768,
                                                     nullptr, scratch, 768, 256);
      attn_v5<<<dim3(4,8,8), 512, 0, stream>>>(scratch, hb);   // hb consumed by gemm above
    } else {
      for (int c=0; c<4; c++){           // 2 batches per chunk (6 MB scratch)
        float* hrows = hb + (size_t)c*2048*256;
        gemm_v2<128,0><<<dim3(6,16), 256, 0, stream>>>(hrows, Wq, bqkv+l*768,
                                                       nullptr, scratch, 768, 256);
        attn_v5<<<dim3(4,8,2), 512, 0, stream>>>(scratch, hrows);
      }
    }
    gemm_v2<64,2><<<dim3(4,64), 256, 0, stream>>>(hb, Wl, bo+l*256, zf, zf, 256, 256);

    ln_fast<<<8192, 256, 0, stream>>>(zf, ln2g+l*256, ln2b+l*256, hb);
    if (bigws){
      for (int c=0; c<2; c++){           // 4-batch FF chunks (ffh 16 MB scratch)
        float* hrows = hb + (size_t)c*4096*256;
        float* zrows = zf + (size_t)c*4096*256;
        gemm_v2<128,1><<<dim3(8,32), 256, 0, stream>>>(hrows, W1, bff1+l*1024,
                                                       nullptr, scratch, 1024, 256);
        gemm_v2<64,2><<<dim3(4,32), 256, 0, stream>>>(scratch, W2, bff2+l*256,
                                                      zrows, zrows, 256, 1024);
      }
    } else {
      for (int c=0; c<4; c++){           // 2-batch FF chunks (ffh 8 MB scratch)
        float* hrows = hb + (size_t)c*2048*256;
        float* zrows = zf + (size_t)c*2048*256;
        gemm_v2<128,1><<<dim3(8,16), 256, 0, stream>>>(hrows, W1, bff1+l*1024,
                                                       nullptr, scratch, 1024, 256);
        gemm_v2<64,2><<<dim3(4,16), 256, 0, stream>>>(scratch, W2, bff2+l*256,
                                                      zrows, zrows, 256, 1024);
      }
    }
  }
}

// Round 7
// 1941.627 us; speedup vs baseline: 8.8067x; 1.4159x over previous
//
#include <hip/hip_runtime.h>

typedef short short8 __attribute__((ext_vector_type(8)));
typedef float f32x4 __attribute__((ext_vector_type(4)));
typedef unsigned short u16x4 __attribute__((ext_vector_type(4)));

// f32 -> bf16 bits (round-to-nearest-even; finite inputs only)
__device__ __forceinline__ unsigned short f2bf(float x){
  unsigned int u = __float_as_uint(x);
  u = u + 0x7FFFu + ((u >> 16) & 1u);
  return (unsigned short)(u >> 16);
}
__device__ __forceinline__ float bf2f(unsigned short h){
  return __uint_as_float(((unsigned int)h) << 16);
}

// ---------------------------------------------------------------- encoder
__global__ __launch_bounds__(256) void encoder_kernel(
    const float* __restrict__ xc, const float* __restrict__ yc, const float* __restrict__ xt,
    const float* __restrict__ W1, const float* __restrict__ b1,
    const float* __restrict__ W2, const float* __restrict__ b2,
    float* __restrict__ z)
{
  __shared__ float zin[10];
  __shared__ float hid[256];
  int blk = blockIdx.x; int b = blk>>10; int t = blk & 1023;
  int tid = threadIdx.x;
  if (tid < 10){
    float v;
    if (tid < 8)      v = (t<512) ? xc[((size_t)b*512+t)*8+tid] : xt[((size_t)b*512+(t-512))*8+tid];
    else if (tid==8)  v = (t<512) ? yc[(size_t)b*512+t] : 0.f;
    else              v = (t<512) ? 0.f : 1.f;
    zin[tid]=v;
  }
  __syncthreads();
  float s = b1[tid];
  #pragma unroll
  for (int i=0;i<10;i++) s += zin[i]*W1[i*256+tid];
  hid[tid] = fmaxf(s, 0.f);
  __syncthreads();
  float o = b2[tid];
  for (int j=0;j<256;j++) o += hid[j]*W2[j*256+tid];
  z[((size_t)b*1024+t)*256 + tid] = o;
}

// ---------------------------------------------------------------- layernorm
__global__ __launch_bounds__(256) void ln_fast(const float* __restrict__ z,
    const float* __restrict__ g, const float* __restrict__ be, float* __restrict__ h)
{
  __shared__ float red[256];
  int row = blockIdx.x, tid = threadIdx.x;
  float x = z[(size_t)row*256 + tid];
  red[tid] = x; __syncthreads();
  for (int s=128; s>0; s>>=1){ if (tid<s) red[tid]+=red[tid+s]; __syncthreads(); }
  float mu = red[0] * (1.f/256.f); __syncthreads();
  float d = x - mu;
  red[tid] = d*d; __syncthreads();
  for (int s=128; s>0; s>>=1){ if (tid<s) red[tid]+=red[tid+s]; __syncthreads(); }
  float var = red[0] * (1.f/256.f);
  float r = rsqrtf(var + 1e-5f);
  h[(size_t)row*256+tid] = d*r*g[tid] + be[tid];
}

// ---------------------------------------------------------------- gemm_mfma
// out[M x N] = EPI(A @ B + bias); A,B,out f32 in HBM.
// Split-bf16 MFMA: x = hi + lo (bf16 each); x*y ~= hh + hl + lh (3 MFMAs,
// ~2^-16 rel err; lo*lo dropped). Useful ceiling 2495/3 ~ 830 TF vs the f32
// vector path's LDS-BW cap (~78 TF) that bounded gemm v1/v2.
// Block 128x128 (4 waves 2x2, wave 64x64 = 4x4 16x16-tiles), K-step 32.
// Split at LDS stage-in (amortized over 128 reuses). LDS rows 40 ushort
// (80 B: b128-aligned, 20-dword stride -> 2-way alias = free) + XOR-8
// k-block swizzle to break stride-16-row write conflicts.
// Frag layouts (gfx950 16x16x32): A/B lane&15 = row/col, k = (lane>>4)*8+j;
// C/D col = lane&15, row = (lane>>4)*4 + reg  [m89-verified].
// Requires M%128==0, N%128==0, K%32==0. No launch-bounds min-waves (R4/R5
// lesson: it caps VGPRs at 256/W and spills the accumulators).
template<int EPI>
__global__ __launch_bounds__(256) void gemm_mfma(
    const float* __restrict__ A, const float* __restrict__ B,
    const float* __restrict__ bias, const float* __restrict__ resid,
    float* __restrict__ out, int N, int K)
{
  constexpr int LDR = 40;
  __shared__ unsigned short Ah[128*LDR], Al[128*LDR];
  __shared__ unsigned short Bh[128*LDR], Bl[128*LDR];

  const int tid = threadIdx.x;
  const int lane = tid & 63, wv = tid >> 6;
  const int wm0 = (wv >> 1) * 64, wn0 = (wv & 1) * 64;
  const int m0 = blockIdx.y * 128, n0 = blockIdx.x * 128;

  // staging maps: A: thread covers (row sar, k sak..sak+15); B: (k-row sbk, n sbn..sbn+15)
  const int sar = tid >> 1, sak = (tid & 1) * 16;
  const int sbk = tid >> 3, sbn = (tid & 7) * 16;
  const int cA = ((sar >> 3) & 3) << 3;
  const int cB = ((sbn >> 4) & 3) << 3;

  const float* Ap = A + (size_t)(m0 + sar) * K + sak;
  const float* Bp = B + (size_t)sbk * N + n0 + sbn;

  const int rowb = lane & 15, kb = (lane >> 4) * 8;

  f32x4 acc[4][4] = {};
  float4 pa[4], pb[4];
  const int NT = K / 32;

  // prologue: load + stage slab 0
  #pragma unroll
  for (int g = 0; g < 4; ++g) pa[g] = *(const float4*)&Ap[g * 4];
  #pragma unroll
  for (int g = 0; g < 4; ++g) pb[g] = *(const float4*)&Bp[g * 4];

  #pragma unroll
  for (int g = 0; g < 4; ++g){
    int idx = sar * LDR + ((sak + g * 4) ^ cA);
    float xs[4] = {pa[g].x, pa[g].y, pa[g].z, pa[g].w};
    u16x4 h, l;
    #pragma unroll
    for (int e = 0; e < 4; ++e){
      unsigned short hb_ = f2bf(xs[e]);
      h[e] = hb_; l[e] = f2bf(xs[e] - bf2f(hb_));
    }
    *(u16x4*)&Ah[idx] = h; *(u16x4*)&Al[idx] = l;
  }
  {
    int kx = sbk ^ cB;
    #pragma unroll
    for (int g = 0; g < 4; ++g){
      float xs[4] = {pb[g].x, pb[g].y, pb[g].z, pb[g].w};
      #pragma unroll
      for (int e = 0; e < 4; ++e){
        int n = sbn + g * 4 + e;
        unsigned short hb_ = f2bf(xs[e]);
        Bh[n * LDR + kx] = hb_;
        Bl[n * LDR + kx] = f2bf(xs[e] - bf2f(hb_));
      }
    }
  }
  __syncthreads();

  for (int t = 0; t < NT; ++t){
    if (t + 1 < NT){
      const float* Ap2 = Ap + (t + 1) * 32;
      const float* Bp2 = Bp + (size_t)(t + 1) * 32 * N;
      #pragma unroll
      for (int g = 0; g < 4; ++g) pa[g] = *(const float4*)&Ap2[g * 4];
      #pragma unroll
      for (int g = 0; g < 4; ++g) pb[g] = *(const float4*)&Bp2[g * 4];
    }
    // B fragments (4 col-tiles x hi/lo), then stream A row-tiles
    short8 bh[4], bl[4];
    #pragma unroll
    for (int ct = 0; ct < 4; ++ct){
      int n = wn0 + ct * 16 + rowb;
      int idx = n * LDR + (kb ^ (((n >> 4) & 3) << 3));
      bh[ct] = *(const short8*)&Bh[idx];
      bl[ct] = *(const short8*)&Bl[idx];
    }
    #pragma unroll
    for (int rt = 0; rt < 4; ++rt){
      int r = wm0 + rt * 16 + rowb;
      int idx = r * LDR + (kb ^ (((r >> 3) & 3) << 3));
      short8 ah = *(const short8*)&Ah[idx];
      short8 al = *(const short8*)&Al[idx];
      #pragma unroll
      for (int ct = 0; ct < 4; ++ct){
        acc[rt][ct] = __builtin_amdgcn_mfma_f32_16x16x32_bf16(ah, bh[ct], acc[rt][ct], 0, 0, 0);
        acc[rt][ct] = __builtin_amdgcn_mfma_f32_16x16x32_bf16(ah, bl[ct], acc[rt][ct], 0, 0, 0);
        acc[rt][ct] = __builtin_amdgcn_mfma_f32_16x16x32_bf16(al, bh[ct], acc[rt][ct], 0, 0, 0);
      }
    }
    if (t + 1 < NT){
      __syncthreads();
      #pragma unroll
      for (int g = 0; g < 4; ++g){
        int idx = sar * LDR + ((sak + g * 4) ^ cA);
        float xs[4] = {pa[g].x, pa[g].y, pa[g].z, pa[g].w};
        u16x4 h, l;
        #pragma unroll
        for (int e = 0; e < 4; ++e){
          unsigned short hb_ = f2bf(xs[e]);
          h[e] = hb_; l[e] = f2bf(xs[e] - bf2f(hb_));
        }
        *(u16x4*)&Ah[idx] = h; *(u16x4*)&Al[idx] = l;
      }
      {
        int kx = sbk ^ cB;
        #pragma unroll
        for (int g = 0; g < 4; ++g){
          float xs[4] = {pb[g].x, pb[g].y, pb[g].z, pb[g].w};
          #pragma unroll
          for (int e = 0; e < 4; ++e){
            int n = sbn + g * 4 + e;
            unsigned short hb_ = f2bf(xs[e]);
            Bh[n * LDR + kx] = hb_;
            Bl[n * LDR + kx] = f2bf(xs[e] - bf2f(hb_));
          }
        }
      }
      __syncthreads();
    }
  }

  // epilogue: C/D layout col=lane&15, row=(lane>>4)*4+q
  #pragma unroll
  for (int ct = 0; ct < 4; ++ct){
    int gc = n0 + wn0 + ct * 16 + rowb;
    float bv = bias[gc];
    #pragma unroll
    for (int rt = 0; rt < 4; ++rt){
      int gr0 = m0 + wm0 + rt * 16 + (lane >> 4) * 4;
      #pragma unroll
      for (int q = 0; q < 4; ++q){
        size_t off = (size_t)(gr0 + q) * N + gc;
        float v = acc[rt][ct][q] + bv;
        if (EPI == 1) v = fmaxf(v, 0.f);
        if (EPI == 2) v += resid[off];
        out[off] = v;
      }
    }
  }
}

// ---------------------------------------------------------------- attention v5
// One thread = one full (q,h) row; Q[32] and acc[32] in registers.
// Whole K/V head-slice staged once in LDS (128 KB); all LDS reads are
// same-address broadcasts; zero cross-lane ops / global loads in the loop.
__global__ __launch_bounds__(512, 2) void attn_v5(
    const float* __restrict__ qkv, float* __restrict__ o)
{
  __shared__ float Ks[512*32];   // 64 KB
  __shared__ float Vs[512*32];   // 64 KB
  const int tid = threadIdx.x;
  const int qg = blockIdx.x, h = blockIdx.y, b = blockIdx.z;
  const int qi = tid & 255;
  const int kg = tid >> 8;             // 0: keys 0..255, 1: keys 256..511
  const int q  = qg*256 + qi;
  const float* base = qkv + (size_t)b*1024*768;
  const int hoff = h*32;
  const float sc = 0.17677669529663687f;   // 1/sqrt(32)

  #pragma unroll
  for (int t = 0; t < 8; ++t){
    int i = tid + t*512;
    int row = i >> 3, c4 = (i & 7)*4;
    *(float4*)&Ks[row*32 + c4] = *(const float4*)&base[(size_t)row*768 + 256 + hoff + c4];
  }
  #pragma unroll
  for (int t = 0; t < 8; ++t){
    int i = tid + t*512;
    int row = i >> 3, c4 = (i & 7)*4;
    *(float4*)&Vs[row*32 + c4] = *(const float4*)&base[(size_t)row*768 + 512 + hoff + c4];
  }

  float Q[32];
  {
    const float4* qp = (const float4*)&base[(size_t)q*768 + hoff];
    #pragma unroll
    for (int p=0;p<8;p++){
      float4 t = qp[p];
      Q[p*4+0]=t.x*sc; Q[p*4+1]=t.y*sc; Q[p*4+2]=t.z*sc; Q[p*4+3]=t.w*sc;
    }
  }
  __syncthreads();

  float m = -1e30f, l = 0.f;
  float acc[32];
  #pragma unroll
  for (int d=0;d<32;d++) acc[d]=0.f;

  const int j0 = kg*256;
  for (int jj=0; jj<256; jj+=2){
    const float* k0 = &Ks[(j0+jj)*32];
    const float* k1 = &Ks[(j0+jj+1)*32];
    float s00=0.f,s01=0.f,s02=0.f,s03=0.f, s10=0.f,s11=0.f,s12=0.f,s13=0.f;
    #pragma unroll
    for (int p=0;p<8;p++){
      float4 a = *(const float4*)&k0[p*4];
      float4 c = *(const float4*)&k1[p*4];
      s00 += Q[p*4+0]*a.x; s01 += Q[p*4+1]*a.y;
      s02 += Q[p*4+2]*a.z; s03 += Q[p*4+3]*a.w;
      s10 += Q[p*4+0]*c.x; s11 += Q[p*4+1]*c.y;
      s12 += Q[p*4+2]*c.z; s13 += Q[p*4+3]*c.w;
    }
    float d0 = (s00+s01)+(s02+s03);
    float d1 = (s10+s11)+(s12+s13);
    float mn = fmaxf(m, fmaxf(d0,d1));
    float corr = __expf(m-mn);
    float p0 = __expf(d0-mn), p1 = __expf(d1-mn);
    l = l*corr + p0 + p1;
    const float* v0 = &Vs[(j0+jj)*32];
    const float* v1 = &Vs[(j0+jj+1)*32];
    #pragma unroll
    for (int p=0;p<8;p++){
      float4 e = *(const float4*)&v0[p*4];
      float4 f = *(const float4*)&v1[p*4];
      acc[p*4+0] = acc[p*4+0]*corr + p0*e.x + p1*f.x;
      acc[p*4+1] = acc[p*4+1]*corr + p0*e.y + p1*f.y;
      acc[p*4+2] = acc[p*4+2]*corr + p0*e.z + p1*f.z;
      acc[p*4+3] = acc[p*4+3]*corr + p0*e.w + p1*f.w;
    }
    m = mn;
  }

  if (kg==1 && q >= 512){
    const float4* kp = (const float4*)&base[(size_t)q*768 + 256 + hoff];
    float s0=0.f,s1=0.f,s2=0.f,s3=0.f;
    #pragma unroll
    for (int p=0;p<8;p++){
      float4 t = kp[p];
      s0 += Q[p*4+0]*t.x; s1 += Q[p*4+1]*t.y;
      s2 += Q[p*4+2]*t.z; s3 += Q[p*4+3]*t.w;
    }
    float d0 = (s0+s1)+(s2+s3);
    float mn = fmaxf(m, d0);
    float corr = __expf(m-mn);
    float p0 = __expf(d0-mn);
    l = l*corr + p0;
    const float4* vp = (const float4*)&base[(size_t)q*768 + 512 + hoff];
    #pragma unroll
    for (int p=0;p<8;p++){
      float4 e = vp[p];
      acc[p*4+0]=acc[p*4+0]*corr + p0*e.x;
      acc[p*4+1]=acc[p*4+1]*corr + p0*e.y;
      acc[p*4+2]=acc[p*4+2]*corr + p0*e.z;
      acc[p*4+3]=acc[p*4+3]*corr + p0*e.w;
    }
    m = mn;
  }

  __syncthreads();
  if (kg==1){
    float* pp = &Ks[(size_t)qi*36];
    #pragma unroll
    for (int d=0;d<32;d++) pp[d]=acc[d];
    pp[32]=m; pp[33]=l;
  }
  __syncthreads();
  if (kg==0){
    const float* pp = &Ks[(size_t)qi*36];
    float m2 = pp[32], l2 = pp[33];
    float mn = fmaxf(m, m2);
    float c1 = __expf(m-mn), c2 = __expf(m2-mn);
    float inv = 1.f/(l*c1 + l2*c2);
    float* op = o + ((size_t)b*1024 + q)*256 + hoff;
    #pragma unroll
    for (int p=0;p<8;p++){
      float4 t;
      t.x = (acc[p*4+0]*c1 + pp[p*4+0]*c2)*inv;
      t.y = (acc[p*4+1]*c1 + pp[p*4+1]*c2)*inv;
      t.z = (acc[p*4+2]*c1 + pp[p*4+2]*c2)*inv;
      t.w = (acc[p*4+3]*c1 + pp[p*4+3]*c2)*inv;
      *(float4*)&op[p*4] = t;
    }
  }
}

// ---------------------------------------------------------------- launch
extern "C" void kernel_launch(void* const* d_in, const int* in_sizes, int n_in,
                              void* d_out, int out_size, void* d_ws, size_t ws_size,
                              hipStream_t stream)
{
  (void)in_sizes; (void)n_in; (void)out_size;
  const float* xc   = (const float*)d_in[0];
  const float* yc   = (const float*)d_in[1];
  const float* xt   = (const float*)d_in[2];
  const float* eW1  = (const float*)d_in[3];
  const float* eb1  = (const float*)d_in[4];
  const float* eW2  = (const float*)d_in[5];
  const float* eb2  = (const float*)d_in[6];
  const float* Wqkv = (const float*)d_in[7];
  const float* bqkv = (const float*)d_in[8];
  const float* Wo   = (const float*)d_in[9];
  const float* bo   = (const float*)d_in[10];
  const float* ln1g = (const float*)d_in[11];
  const float* ln1b = (const float*)d_in[12];
  const float* ln2g = (const float*)d_in[13];
  const float* ln2b = (const float*)d_in[14];
  const float* Wff1 = (const float*)d_in[15];
  const float* bff1 = (const float*)d_in[16];
  const float* Wff2 = (const float*)d_in[17];
  const float* bff2 = (const float*)d_in[18];

  float* zf = (float*)d_out;            // residual stream [8][1024][256] f32 = 8 MB
  char* ws = (char*)d_ws;
  float* hb      = (float*)(ws);                        // 8 MB (LN out / attn out)
  float* scratch = (float*)(ws + (size_t)8*1024*1024);  // qkv / ffh

  const bool bigws = (ws_size == 0) || (ws_size >= (size_t)33*1024*1024);

  encoder_kernel<<<8192, 256, 0, stream>>>(xc, yc, xt, eW1, eb1, eW2, eb2, zf);

  for (int l=0; l<6; l++){
    const float* Wq = Wqkv + (size_t)l*256*768;
    const float* Wl = Wo   + (size_t)l*256*256;
    const float* W1 = Wff1 + (size_t)l*256*1024;
    const float* W2 = Wff2 + (size_t)l*1024*256;

    ln_fast<<<8192, 256, 0, stream>>>(zf, ln1g+l*256, ln1b+l*256, hb);
    if (bigws){
      gemm_mfma<0><<<dim3(6,64), 256, 0, stream>>>(hb, Wq, bqkv+l*768,
                                                   nullptr, scratch, 768, 256);
      attn_v5<<<dim3(4,8,8), 512, 0, stream>>>(scratch, hb);
    } else {
      for (int c=0; c<4; c++){           // 2 batches per chunk (6 MB scratch)
        float* hrows = hb + (size_t)c*2048*256;
        gemm_mfma<0><<<dim3(6,16), 256, 0, stream>>>(hrows, Wq, bqkv+l*768,
                                                     nullptr, scratch, 768, 256);
        attn_v5<<<dim3(4,8,2), 512, 0, stream>>>(scratch, hrows);
      }
    }
    gemm_mfma<2><<<dim3(2,64), 256, 0, stream>>>(hb, Wl, bo+l*256, zf, zf, 256, 256);

    ln_fast<<<8192, 256, 0, stream>>>(zf, ln2g+l*256, ln2b+l*256, hb);
    if (bigws){
      for (int c=0; c<2; c++){           // 4-batch FF chunks (ffh 16 MB scratch)
        float* hrows = hb + (size_t)c*4096*256;
        float* zrows = zf + (size_t)c*4096*256;
        gemm_mfma<1><<<dim3(8,32), 256, 0, stream>>>(hrows, W1, bff1+l*1024,
                                                     nullptr, scratch, 1024, 256);
        gemm_mfma<2><<<dim3(2,32), 256, 0, stream>>>(scratch, W2, bff2+l*256,
                                                     zrows, zrows, 256, 1024);
      }
    } else {
      for (int c=0; c<4; c++){           // 2-batch FF chunks (ffh 8 MB scratch)
        float* hrows = hb + (size_t)c*2048*256;
        float* zrows = zf + (size_t)c*2048*256;
        gemm_mfma<1><<<dim3(8,16), 256, 0, stream>>>(hrows, W1, bff1+l*1024,
                                                     nullptr, scratch, 1024, 256);
        gemm_mfma<2><<<dim3(2,16), 256, 0, stream>>>(scratch, W2, bff2+l*256,
                                                     zrows, zrows, 256, 1024);
      }
    }
  }
}

// Round 8
// 1529.452 us; speedup vs baseline: 11.1800x; 1.2695x over previous
//
#include <hip/hip_runtime.h>

typedef short short8 __attribute__((ext_vector_type(8)));
typedef float f32x4 __attribute__((ext_vector_type(4)));
typedef unsigned short u16x4 __attribute__((ext_vector_type(4)));

// f32 -> bf16 bits (round-to-nearest-even; finite inputs only)
__device__ __forceinline__ unsigned short f2bf(float x){
  unsigned int u = __float_as_uint(x);
  u = u + 0x7FFFu + ((u >> 16) & 1u);
  return (unsigned short)(u >> 16);
}
__device__ __forceinline__ float bf2f(unsigned short h){
  return __uint_as_float(((unsigned int)h) << 16);
}

// ---------------------------------------------------------------- encoder
__global__ __launch_bounds__(256) void encoder_kernel(
    const float* __restrict__ xc, const float* __restrict__ yc, const float* __restrict__ xt,
    const float* __restrict__ W1, const float* __restrict__ b1,
    const float* __restrict__ W2, const float* __restrict__ b2,
    float* __restrict__ z)
{
  __shared__ float zin[10];
  __shared__ float hid[256];
  int blk = blockIdx.x; int b = blk>>10; int t = blk & 1023;
  int tid = threadIdx.x;
  if (tid < 10){
    float v;
    if (tid < 8)      v = (t<512) ? xc[((size_t)b*512+t)*8+tid] : xt[((size_t)b*512+(t-512))*8+tid];
    else if (tid==8)  v = (t<512) ? yc[(size_t)b*512+t] : 0.f;
    else              v = (t<512) ? 0.f : 1.f;
    zin[tid]=v;
  }
  __syncthreads();
  float s = b1[tid];
  #pragma unroll
  for (int i=0;i<10;i++) s += zin[i]*W1[i*256+tid];
  hid[tid] = fmaxf(s, 0.f);
  __syncthreads();
  float o = b2[tid];
  for (int j=0;j<256;j++) o += hid[j]*W2[j*256+tid];
  z[((size_t)b*1024+t)*256 + tid] = o;
}

// ---------------------------------------------------------------- layernorm
__global__ __launch_bounds__(256) void ln_fast(const float* __restrict__ z,
    const float* __restrict__ g, const float* __restrict__ be, float* __restrict__ h)
{
  __shared__ float red[256];
  int row = blockIdx.x, tid = threadIdx.x;
  float x = z[(size_t)row*256 + tid];
  red[tid] = x; __syncthreads();
  for (int s=128; s>0; s>>=1){ if (tid<s) red[tid]+=red[tid+s]; __syncthreads(); }
  float mu = red[0] * (1.f/256.f); __syncthreads();
  float d = x - mu;
  red[tid] = d*d; __syncthreads();
  for (int s=128; s>0; s>>=1){ if (tid<s) red[tid]+=red[tid+s]; __syncthreads(); }
  float var = red[0] * (1.f/256.f);
  float r = rsqrtf(var + 1e-5f);
  h[(size_t)row*256+tid] = d*r*g[tid] + be[tid];
}

// ---------------------------------------------------------------- gemm_mfma
// (unchanged from round 7 — verified) split-bf16 MFMA GEMM, 128x128 block.
template<int EPI>
__global__ __launch_bounds__(256) void gemm_mfma(
    const float* __restrict__ A, const float* __restrict__ B,
    const float* __restrict__ bias, const float* __restrict__ resid,
    float* __restrict__ out, int N, int K)
{
  constexpr int LDR = 40;
  __shared__ unsigned short Ah[128*LDR], Al[128*LDR];
  __shared__ unsigned short Bh[128*LDR], Bl[128*LDR];

  const int tid = threadIdx.x;
  const int lane = tid & 63, wv = tid >> 6;
  const int wm0 = (wv >> 1) * 64, wn0 = (wv & 1) * 64;
  const int m0 = blockIdx.y * 128, n0 = blockIdx.x * 128;

  const int sar = tid >> 1, sak = (tid & 1) * 16;
  const int sbk = tid >> 3, sbn = (tid & 7) * 16;
  const int cA = ((sar >> 3) & 3) << 3;
  const int cB = ((sbn >> 4) & 3) << 3;

  const float* Ap = A + (size_t)(m0 + sar) * K + sak;
  const float* Bp = B + (size_t)sbk * N + n0 + sbn;

  const int rowb = lane & 15, kb = (lane >> 4) * 8;

  f32x4 acc[4][4] = {};
  float4 pa[4], pb[4];
  const int NT = K / 32;

  #pragma unroll
  for (int g = 0; g < 4; ++g) pa[g] = *(const float4*)&Ap[g * 4];
  #pragma unroll
  for (int g = 0; g < 4; ++g) pb[g] = *(const float4*)&Bp[g * 4];

  #pragma unroll
  for (int g = 0; g < 4; ++g){
    int idx = sar * LDR + ((sak + g * 4) ^ cA);
    float xs[4] = {pa[g].x, pa[g].y, pa[g].z, pa[g].w};
    u16x4 h, l;
    #pragma unroll
    for (int e = 0; e < 4; ++e){
      unsigned short hb_ = f2bf(xs[e]);
      h[e] = hb_; l[e] = f2bf(xs[e] - bf2f(hb_));
    }
    *(u16x4*)&Ah[idx] = h; *(u16x4*)&Al[idx] = l;
  }
  {
    int kx = sbk ^ cB;
    #pragma unroll
    for (int g = 0; g < 4; ++g){
      float xs[4] = {pb[g].x, pb[g].y, pb[g].z, pb[g].w};
      #pragma unroll
      for (int e = 0; e < 4; ++e){
        int n = sbn + g * 4 + e;
        unsigned short hb_ = f2bf(xs[e]);
        Bh[n * LDR + kx] = hb_;
        Bl[n * LDR + kx] = f2bf(xs[e] - bf2f(hb_));
      }
    }
  }
  __syncthreads();

  for (int t = 0; t < NT; ++t){
    if (t + 1 < NT){
      const float* Ap2 = Ap + (t + 1) * 32;
      const float* Bp2 = Bp + (size_t)(t + 1) * 32 * N;
      #pragma unroll
      for (int g = 0; g < 4; ++g) pa[g] = *(const float4*)&Ap2[g * 4];
      #pragma unroll
      for (int g = 0; g < 4; ++g) pb[g] = *(const float4*)&Bp2[g * 4];
    }
    short8 bh[4], bl[4];
    #pragma unroll
    for (int ct = 0; ct < 4; ++ct){
      int n = wn0 + ct * 16 + rowb;
      int idx = n * LDR + (kb ^ (((n >> 4) & 3) << 3));
      bh[ct] = *(const short8*)&Bh[idx];
      bl[ct] = *(const short8*)&Bl[idx];
    }
    #pragma unroll
    for (int rt = 0; rt < 4; ++rt){
      int r = wm0 + rt * 16 + rowb;
      int idx = r * LDR + (kb ^ (((r >> 3) & 3) << 3));
      short8 ah = *(const short8*)&Ah[idx];
      short8 al = *(const short8*)&Al[idx];
      #pragma unroll
      for (int ct = 0; ct < 4; ++ct){
        acc[rt][ct] = __builtin_amdgcn_mfma_f32_16x16x32_bf16(ah, bh[ct], acc[rt][ct], 0, 0, 0);
        acc[rt][ct] = __builtin_amdgcn_mfma_f32_16x16x32_bf16(ah, bl[ct], acc[rt][ct], 0, 0, 0);
        acc[rt][ct] = __builtin_amdgcn_mfma_f32_16x16x32_bf16(al, bh[ct], acc[rt][ct], 0, 0, 0);
      }
    }
    if (t + 1 < NT){
      __syncthreads();
      #pragma unroll
      for (int g = 0; g < 4; ++g){
        int idx = sar * LDR + ((sak + g * 4) ^ cA);
        float xs[4] = {pa[g].x, pa[g].y, pa[g].z, pa[g].w};
        u16x4 h, l;
        #pragma unroll
        for (int e = 0; e < 4; ++e){
          unsigned short hb_ = f2bf(xs[e]);
          h[e] = hb_; l[e] = f2bf(xs[e] - bf2f(hb_));
        }
        *(u16x4*)&Ah[idx] = h; *(u16x4*)&Al[idx] = l;
      }
      {
        int kx = sbk ^ cB;
        #pragma unroll
        for (int g = 0; g < 4; ++g){
          float xs[4] = {pb[g].x, pb[g].y, pb[g].z, pb[g].w};
          #pragma unroll
          for (int e = 0; e < 4; ++e){
            int n = sbn + g * 4 + e;
            unsigned short hb_ = f2bf(xs[e]);
            Bh[n * LDR + kx] = hb_;
            Bl[n * LDR + kx] = f2bf(xs[e] - bf2f(hb_));
          }
        }
      }
      __syncthreads();
    }
  }

  #pragma unroll
  for (int ct = 0; ct < 4; ++ct){
    int gc = n0 + wn0 + ct * 16 + rowb;
    float bv = bias[gc];
    #pragma unroll
    for (int rt = 0; rt < 4; ++rt){
      int gr0 = m0 + wm0 + rt * 16 + (lane >> 4) * 4;
      #pragma unroll
      for (int q = 0; q < 4; ++q){
        size_t off = (size_t)(gr0 + q) * N + gc;
        float v = acc[rt][ct][q] + bv;
        if (EPI == 1) v = fmaxf(v, 0.f);
        if (EPI == 2) v += resid[off];
        out[off] = v;
      }
    }
  }
}

// ---------------------------------------------------------------- attention v6 (MFMA flash)
// Swapped-QK flash attention on the matrix pipe. Per wave: 16 q-rows.
// S = mfma(K,Q) (K as A-operand) -> S col=lane&15=q, row=key: P lands directly
// in the A-operand layout for the PV MFMA (zero cross-lane ops in the loop).
// Interleaved key->frag-row map (key = st*32 + (i>>2)*8 + (i&3), half +4) so
// two 16-key S-MFMAs fill one K=32 P-fragment. QK^T is split-bf16 (3 MFMAs,
// ~2^-16); P and V plain bf16 (P in [0,1]; final-output error ~1e-3).
// K(hi/lo) + V^T staged once per block in LDS (114 KB bf16). 8 waves/block.
// Rescale of O only when the running max grows (ballot-guarded, exact);
// per-q corr/inv redistributed S-layout->O-layout via a per-wave LDS slot.
// Targets (qc>=4) self-attend via one masked diagonal tile from global.
// All fragment layouts identical to gemm_mfma's (HW-verified in round 7).
__global__ __launch_bounds__(512) void attn_v6(
    const float* __restrict__ qkv, float* __restrict__ o)
{
  constexpr int LDK = 40;    // ushorts per K row (80 B, 16B-aligned)
  constexpr int LDV = 520;   // ushorts per Vt row
  __shared__ unsigned short Khi[512*LDK];   // 40 KB
  __shared__ unsigned short Klo[512*LDK];   // 40 KB
  __shared__ unsigned short Vt[32*LDV];     // 32.5 KB
  __shared__ float cbuf[8][16];

  const int tid = threadIdx.x;
  const int qc = blockIdx.x, h = blockIdx.y, b = blockIdx.z;
  const float* base = qkv + (size_t)b*1024*768;
  const int hoff = h*32;
  const float sc = 0.17677669529663687f;   // 1/sqrt(32)

  // ---- stage K (hi/lo bf16) and V^T (bf16), keys 0..511
  #pragma unroll
  for (int t = 0; t < 8; ++t){
    int i = tid + t*512;
    int row = i >> 3, c4 = (i & 7) * 4;
    float4 kv = *(const float4*)&base[(size_t)row*768 + 256 + hoff + c4];
    float ks[4] = {kv.x, kv.y, kv.z, kv.w};
    u16x4 hk, lk;
    #pragma unroll
    for (int e = 0; e < 4; ++e){
      unsigned short hb_ = f2bf(ks[e]);
      hk[e] = hb_; lk[e] = f2bf(ks[e] - bf2f(hb_));
    }
    *(u16x4*)&Khi[row*LDK + c4] = hk;
    *(u16x4*)&Klo[row*LDK + c4] = lk;
    float4 vv = *(const float4*)&base[(size_t)row*768 + 512 + hoff + c4];
    float vs[4] = {vv.x, vv.y, vv.z, vv.w};
    #pragma unroll
    for (int e = 0; e < 4; ++e)
      Vt[(c4 + e)*LDV + row] = f2bf(vs[e]);
  }

  // ---- per-wave setup
  const int wv = tid >> 6, lane = tid & 63;
  const int g = lane >> 4, r = lane & 15;
  const int q0w = qc*128 + wv*16;

  // Q fragment (B-operand: col=r=q, k-dims g*8..g*8+7), scaled, split hi/lo
  short8 qh, ql;
  {
    const float* qp = &base[(size_t)(q0w + r)*768 + hoff + g*8];
    float4 a = *(const float4*)qp;
    float4 c = *(const float4*)(qp + 4);
    float xs[8] = {a.x*sc, a.y*sc, a.z*sc, a.w*sc, c.x*sc, c.y*sc, c.z*sc, c.w*sc};
    #pragma unroll
    for (int e = 0; e < 8; ++e){
      unsigned short hb_ = f2bf(xs[e]);
      qh[e] = (short)hb_;
      ql[e] = (short)f2bf(xs[e] - bf2f(hb_));
    }
  }
  __syncthreads();

  float m = -1e30f, l = 0.f;
  f32x4 O0 = {0.f,0.f,0.f,0.f}, O1 = {0.f,0.f,0.f,0.f};

  for (int st = 0; st < 16; ++st){
    // two S-halves: A-frag row i -> key st*32 + (i>>2)*8 + (i&3) (+4 for half1)
    int key0 = st*32 + (r >> 2)*8 + (r & 3);
    short8 ah0 = *(const short8*)&Khi[key0*LDK + g*8];
    short8 al0 = *(const short8*)&Klo[key0*LDK + g*8];
    short8 ah1 = *(const short8*)&Khi[(key0+4)*LDK + g*8];
    short8 al1 = *(const short8*)&Klo[(key0+4)*LDK + g*8];
    f32x4 s0 = {0.f,0.f,0.f,0.f}, s1 = {0.f,0.f,0.f,0.f};
    s0 = __builtin_amdgcn_mfma_f32_16x16x32_bf16(ah0, qh, s0, 0,0,0);
    s0 = __builtin_amdgcn_mfma_f32_16x16x32_bf16(ah0, ql, s0, 0,0,0);
    s0 = __builtin_amdgcn_mfma_f32_16x16x32_bf16(al0, qh, s0, 0,0,0);
    s1 = __builtin_amdgcn_mfma_f32_16x16x32_bf16(ah1, qh, s1, 0,0,0);
    s1 = __builtin_amdgcn_mfma_f32_16x16x32_bf16(ah1, ql, s1, 0,0,0);
    s1 = __builtin_amdgcn_mfma_f32_16x16x32_bf16(al1, qh, s1, 0,0,0);
    // lane holds p for q=r, phys keys st*32 + g*8 + j (j<4: s0[j], j>=4: s1[j-4])
    float pv[8] = {s0[0],s0[1],s0[2],s0[3], s1[0],s1[1],s1[2],s1[3]};
    float tm = pv[0];
    #pragma unroll
    for (int j = 1; j < 8; ++j) tm = fmaxf(tm, pv[j]);
    tm = fmaxf(tm, __shfl_xor(tm, 16));
    tm = fmaxf(tm, __shfl_xor(tm, 32));
    float mn = fmaxf(m, tm);
    float ts = 0.f;
    #pragma unroll
    for (int j = 0; j < 8; ++j){ pv[j] = __expf(pv[j] - mn); ts += pv[j]; }
    ts += __shfl_xor(ts, 16);
    ts += __shfl_xor(ts, 32);
    if (__any(mn > m)){
      float corr = __expf(m - mn);
      if (lane < 16) cbuf[wv][lane] = corr;
      asm volatile("s_waitcnt lgkmcnt(0)" ::: "memory");
      f32x4 cf = *(const f32x4*)&cbuf[wv][g*4];
      #pragma unroll
      for (int j = 0; j < 4; ++j){ O0[j] *= cf[j]; O1[j] *= cf[j]; }
      l *= corr;
      m = mn;
    }
    l += ts;
    short8 pa;
    #pragma unroll
    for (int j = 0; j < 8; ++j) pa[j] = (short)f2bf(pv[j]);
    short8 v0 = *(const short8*)&Vt[(size_t)r*LDV + st*32 + g*8];
    short8 v1 = *(const short8*)&Vt[(size_t)(r+16)*LDV + st*32 + g*8];
    O0 = __builtin_amdgcn_mfma_f32_16x16x32_bf16(pa, v0, O0, 0,0,0);
    O1 = __builtin_amdgcn_mfma_f32_16x16x32_bf16(pa, v1, O1, 0,0,0);
  }

  // ---- self-attend tile (targets only): diagonal-masked, K/V from global
  if (qc >= 4){
    const float* kp = &base[(size_t)(q0w + r)*768 + 256 + hoff + g*8];
    float4 a = *(const float4*)kp;
    float4 c = *(const float4*)(kp + 4);
    float xs[8] = {a.x, a.y, a.z, a.w, c.x, c.y, c.z, c.w};
    short8 ah, al;
    #pragma unroll
    for (int e = 0; e < 8; ++e){
      unsigned short hb_ = f2bf(xs[e]);
      ah[e] = (short)hb_;
      al[e] = (short)f2bf(xs[e] - bf2f(hb_));
    }
    f32x4 s = {0.f,0.f,0.f,0.f};
    s = __builtin_amdgcn_mfma_f32_16x16x32_bf16(ah, qh, s, 0,0,0);
    s = __builtin_amdgcn_mfma_f32_16x16x32_bf16(ah, ql, s, 0,0,0);
    s = __builtin_amdgcn_mfma_f32_16x16x32_bf16(al, qh, s, 0,0,0);
    // D element reg j = S[row=g*4+j][col=r]; allowed iff g*4+j == r
    float pv[8] = {0.f,0.f,0.f,0.f,0.f,0.f,0.f,0.f};
    float tm = -1e30f;
    #pragma unroll
    for (int j = 0; j < 4; ++j){
      bool al_ = (g*4 + j) == r;
      tm = fmaxf(tm, al_ ? s[j] : -1e30f);
    }
    tm = fmaxf(tm, __shfl_xor(tm, 16));
    tm = fmaxf(tm, __shfl_xor(tm, 32));
    float mn = fmaxf(m, tm);
    float ts = 0.f;
    #pragma unroll
    for (int j = 0; j < 4; ++j){
      bool al_ = (g*4 + j) == r;
      pv[j] = al_ ? __expf(s[j] - mn) : 0.f;
      ts += pv[j];
    }
    ts += __shfl_xor(ts, 16);
    ts += __shfl_xor(ts, 32);
    if (__any(mn > m)){
      float corr = __expf(m - mn);
      if (lane < 16) cbuf[wv][lane] = corr;
      asm volatile("s_waitcnt lgkmcnt(0)" ::: "memory");
      f32x4 cf = *(const f32x4*)&cbuf[wv][g*4];
      #pragma unroll
      for (int j = 0; j < 4; ++j){ O0[j] *= cf[j]; O1[j] *= cf[j]; }
      l *= corr;
      m = mn;
    }
    l += ts;
    short8 pa, v0, v1;
    #pragma unroll
    for (int j = 0; j < 8; ++j) pa[j] = (short)f2bf(pv[j]);
    #pragma unroll
    for (int j = 0; j < 4; ++j){
      // P slot j corresponds to self key row q0w + g*4 + j
      const float* vp = &base[(size_t)(q0w + g*4 + j)*768 + 512 + hoff];
      v0[j] = (short)f2bf(vp[r]);
      v1[j] = (short)f2bf(vp[r + 16]);
      v0[j+4] = 0; v1[j+4] = 0;   // p==0 there
    }
    O0 = __builtin_amdgcn_mfma_f32_16x16x32_bf16(pa, v0, O0, 0,0,0);
    O1 = __builtin_amdgcn_mfma_f32_16x16x32_bf16(pa, v1, O1, 0,0,0);
  }

  // ---- normalize and store. O element reg j: q = q0w + g*4 + j, d = r / r+16
  float inv = 1.f / l;
  if (lane < 16) cbuf[wv][lane] = inv;
  asm volatile("s_waitcnt lgkmcnt(0)" ::: "memory");
  f32x4 iv = *(const f32x4*)&cbuf[wv][g*4];
  float* op = o + ((size_t)b*1024 + q0w + g*4)*256 + hoff;
  #pragma unroll
  for (int j = 0; j < 4; ++j){
    op[(size_t)j*256 + r]      = O0[j] * iv[j];
    op[(size_t)j*256 + r + 16] = O1[j] * iv[j];
  }
}

// ---------------------------------------------------------------- launch
extern "C" void kernel_launch(void* const* d_in, const int* in_sizes, int n_in,
                              void* d_out, int out_size, void* d_ws, size_t ws_size,
                              hipStream_t stream)
{
  (void)in_sizes; (void)n_in; (void)out_size;
  const float* xc   = (const float*)d_in[0];
  const float* yc   = (const float*)d_in[1];
  const float* xt   = (const float*)d_in[2];
  const float* eW1  = (const float*)d_in[3];
  const float* eb1  = (const float*)d_in[4];
  const float* eW2  = (const float*)d_in[5];
  const float* eb2  = (const float*)d_in[6];
  const float* Wqkv = (const float*)d_in[7];
  const float* bqkv = (const float*)d_in[8];
  const float* Wo   = (const float*)d_in[9];
  const float* bo   = (const float*)d_in[10];
  const float* ln1g = (const float*)d_in[11];
  const float* ln1b = (const float*)d_in[12];
  const float* ln2g = (const float*)d_in[13];
  const float* ln2b = (const float*)d_in[14];
  const float* Wff1 = (const float*)d_in[15];
  const float* bff1 = (const float*)d_in[16];
  const float* Wff2 = (const float*)d_in[17];
  const float* bff2 = (const float*)d_in[18];

  float* zf = (float*)d_out;            // residual stream [8][1024][256] f32 = 8 MB
  char* ws = (char*)d_ws;
  float* hb      = (float*)(ws);                        // 8 MB (LN out / attn out)
  float* scratch = (float*)(ws + (size_t)8*1024*1024);  // qkv / ffh

  const bool bigws = (ws_size == 0) || (ws_size >= (size_t)33*1024*1024);

  encoder_kernel<<<8192, 256, 0, stream>>>(xc, yc, xt, eW1, eb1, eW2, eb2, zf);

  for (int l=0; l<6; l++){
    const float* Wq = Wqkv + (size_t)l*256*768;
    const float* Wl = Wo   + (size_t)l*256*256;
    const float* W1 = Wff1 + (size_t)l*256*1024;
    const float* W2 = Wff2 + (size_t)l*1024*256;

    ln_fast<<<8192, 256, 0, stream>>>(zf, ln1g+l*256, ln1b+l*256, hb);
    if (bigws){
      gemm_mfma<0><<<dim3(6,64), 256, 0, stream>>>(hb, Wq, bqkv+l*768,
                                                   nullptr, scratch, 768, 256);
      attn_v6<<<dim3(8,8,8), 512, 0, stream>>>(scratch, hb);
    } else {
      for (int c=0; c<4; c++){           // 2 batches per chunk (6 MB scratch)
        float* hrows = hb + (size_t)c*2048*256;
        gemm_mfma<0><<<dim3(6,16), 256, 0, stream>>>(hrows, Wq, bqkv+l*768,
                                                     nullptr, scratch, 768, 256);
        attn_v6<<<dim3(8,8,2), 512, 0, stream>>>(scratch, hrows);
      }
    }
    gemm_mfma<2><<<dim3(2,64), 256, 0, stream>>>(hb, Wl, bo+l*256, zf, zf, 256, 256);

    ln_fast<<<8192, 256, 0, stream>>>(zf, ln2g+l*256, ln2b+l*256, hb);
    if (bigws){
      for (int c=0; c<2; c++){           // 4-batch FF chunks (ffh 16 MB scratch)
        float* hrows = hb + (size_t)c*4096*256;
        float* zrows = zf + (size_t)c*4096*256;
        gemm_mfma<1><<<dim3(8,32), 256, 0, stream>>>(hrows, W1, bff1+l*1024,
                                                     nullptr, scratch, 1024, 256);
        gemm_mfma<2><<<dim3(2,32), 256, 0, stream>>>(scratch, W2, bff2+l*256,
                                                     zrows, zrows, 256, 1024);
      }
    } else {
      for (int c=0; c<4; c++){           // 2-batch FF chunks (ffh 8 MB scratch)
        float* hrows = hb + (size_t)c*2048*256;
        float* zrows = zf + (size_t)c*2048*256;
        gemm_mfma<1><<<dim3(8,16), 256, 0, stream>>>(hrows, W1, bff1+l*1024,
                                                     nullptr, scratch, 1024, 256);
        gemm_mfma<2><<<dim3(2,16), 256, 0, stream>>>(scratch, W2, bff2+l*256,
                                                     zrows, zrows, 256, 1024);
      }
    }
  }
}

// Round 9
// 1350.971 us; speedup vs baseline: 12.6570x; 1.1321x over previous
//
#include <hip/hip_runtime.h>

typedef short short8 __attribute__((ext_vector_type(8)));
typedef float f32x4 __attribute__((ext_vector_type(4)));
typedef unsigned short u16x4 __attribute__((ext_vector_type(4)));

// f32 -> bf16 bits (round-to-nearest-even; finite inputs only)
__device__ __forceinline__ unsigned short f2bf(float x){
  unsigned int u = __float_as_uint(x);
  u = u + 0x7FFFu + ((u >> 16) & 1u);
  return (unsigned short)(u >> 16);
}
__device__ __forceinline__ float bf2f(unsigned short h){
  return __uint_as_float(((unsigned int)h) << 16);
}

// ---------------------------------------------------------------- encoder stage 1
// hid = relu(zin @ W1 + b1), K=10. Stage 2 (256x256 GEMM) goes through
// gemm_mfma (round-8 lesson: the fused scalar version was 84 us of L2 loads).
__global__ __launch_bounds__(256) void encoder_s1(
    const float* __restrict__ xc, const float* __restrict__ yc, const float* __restrict__ xt,
    const float* __restrict__ W1, const float* __restrict__ b1,
    float* __restrict__ hid)
{
  __shared__ float zin[10];
  int blk = blockIdx.x; int b = blk>>10; int t = blk & 1023;
  int tid = threadIdx.x;
  if (tid < 10){
    float v;
    if (tid < 8)      v = (t<512) ? xc[((size_t)b*512+t)*8+tid] : xt[((size_t)b*512+(t-512))*8+tid];
    else if (tid==8)  v = (t<512) ? yc[(size_t)b*512+t] : 0.f;
    else              v = (t<512) ? 0.f : 1.f;
    zin[tid]=v;
  }
  __syncthreads();
  float s = b1[tid];
  #pragma unroll
  for (int i=0;i<10;i++) s += zin[i]*W1[i*256+tid];
  hid[(size_t)blk*256 + tid] = fmaxf(s, 0.f);
}

// ---------------------------------------------------------------- layernorm v2
// One wave per row (4 rows / 256-thread block), shuffle-only reduction,
// float4 loads/stores, zero barriers. Replaces the 8-barrier tree version.
__global__ __launch_bounds__(256) void ln_v2(const float* __restrict__ z,
    const float* __restrict__ g, const float* __restrict__ be, float* __restrict__ h)
{
  const int row = blockIdx.x*4 + (threadIdx.x>>6);
  const int lane = threadIdx.x & 63;
  float4 x = *(const float4*)&z[(size_t)row*256 + lane*4];
  float s = (x.x+x.y)+(x.z+x.w);
  #pragma unroll
  for (int off=32; off; off>>=1) s += __shfl_xor(s, off);
  float mu = s * (1.f/256.f);
  float dx = x.x-mu, dy = x.y-mu, dz = x.z-mu, dw = x.w-mu;
  float v = (dx*dx+dy*dy)+(dz*dz+dw*dw);
  #pragma unroll
  for (int off=32; off; off>>=1) v += __shfl_xor(v, off);
  float r = rsqrtf(v*(1.f/256.f) + 1e-5f);
  float4 gv = *(const float4*)&g[lane*4];
  float4 bv = *(const float4*)&be[lane*4];
  float4 o;
  o.x = dx*r*gv.x + bv.x; o.y = dy*r*gv.y + bv.y;
  o.z = dz*r*gv.z + bv.z; o.w = dw*r*gv.w + bv.w;
  *(float4*)&h[(size_t)row*256 + lane*4] = o;
}

// ---------------------------------------------------------------- gemm_mfma
// (unchanged — verified round 7/8) split-bf16 MFMA GEMM, 128x128 block.
template<int EPI>
__global__ __launch_bounds__(256) void gemm_mfma(
    const float* __restrict__ A, const float* __restrict__ B,
    const float* __restrict__ bias, const float* __restrict__ resid,
    float* __restrict__ out, int N, int K)
{
  constexpr int LDR = 40;
  __shared__ unsigned short Ah[128*LDR], Al[128*LDR];
  __shared__ unsigned short Bh[128*LDR], Bl[128*LDR];

  const int tid = threadIdx.x;
  const int lane = tid & 63, wv = tid >> 6;
  const int wm0 = (wv >> 1) * 64, wn0 = (wv & 1) * 64;
  const int m0 = blockIdx.y * 128, n0 = blockIdx.x * 128;

  const int sar = tid >> 1, sak = (tid & 1) * 16;
  const int sbk = tid >> 3, sbn = (tid & 7) * 16;
  const int cA = ((sar >> 3) & 3) << 3;
  const int cB = ((sbn >> 4) & 3) << 3;

  const float* Ap = A + (size_t)(m0 + sar) * K + sak;
  const float* Bp = B + (size_t)sbk * N + n0 + sbn;

  const int rowb = lane & 15, kb = (lane >> 4) * 8;

  f32x4 acc[4][4] = {};
  float4 pa[4], pb[4];
  const int NT = K / 32;

  #pragma unroll
  for (int g = 0; g < 4; ++g) pa[g] = *(const float4*)&Ap[g * 4];
  #pragma unroll
  for (int g = 0; g < 4; ++g) pb[g] = *(const float4*)&Bp[g * 4];

  #pragma unroll
  for (int g = 0; g < 4; ++g){
    int idx = sar * LDR + ((sak + g * 4) ^ cA);
    float xs[4] = {pa[g].x, pa[g].y, pa[g].z, pa[g].w};
    u16x4 h, l;
    #pragma unroll
    for (int e = 0; e < 4; ++e){
      unsigned short hb_ = f2bf(xs[e]);
      h[e] = hb_; l[e] = f2bf(xs[e] - bf2f(hb_));
    }
    *(u16x4*)&Ah[idx] = h; *(u16x4*)&Al[idx] = l;
  }
  {
    int kx = sbk ^ cB;
    #pragma unroll
    for (int g = 0; g < 4; ++g){
      float xs[4] = {pb[g].x, pb[g].y, pb[g].z, pb[g].w};
      #pragma unroll
      for (int e = 0; e < 4; ++e){
        int n = sbn + g * 4 + e;
        unsigned short hb_ = f2bf(xs[e]);
        Bh[n * LDR + kx] = hb_;
        Bl[n * LDR + kx] = f2bf(xs[e] - bf2f(hb_));
      }
    }
  }
  __syncthreads();

  for (int t = 0; t < NT; ++t){
    if (t + 1 < NT){
      const float* Ap2 = Ap + (t + 1) * 32;
      const float* Bp2 = Bp + (size_t)(t + 1) * 32 * N;
      #pragma unroll
      for (int g = 0; g < 4; ++g) pa[g] = *(const float4*)&Ap2[g * 4];
      #pragma unroll
      for (int g = 0; g < 4; ++g) pb[g] = *(const float4*)&Bp2[g * 4];
    }
    short8 bh[4], bl[4];
    #pragma unroll
    for (int ct = 0; ct < 4; ++ct){
      int n = wn0 + ct * 16 + rowb;
      int idx = n * LDR + (kb ^ (((n >> 4) & 3) << 3));
      bh[ct] = *(const short8*)&Bh[idx];
      bl[ct] = *(const short8*)&Bl[idx];
    }
    #pragma unroll
    for (int rt = 0; rt < 4; ++rt){
      int r = wm0 + rt * 16 + rowb;
      int idx = r * LDR + (kb ^ (((r >> 3) & 3) << 3));
      short8 ah = *(const short8*)&Ah[idx];
      short8 al = *(const short8*)&Al[idx];
      #pragma unroll
      for (int ct = 0; ct < 4; ++ct){
        acc[rt][ct] = __builtin_amdgcn_mfma_f32_16x16x32_bf16(ah, bh[ct], acc[rt][ct], 0, 0, 0);
        acc[rt][ct] = __builtin_amdgcn_mfma_f32_16x16x32_bf16(ah, bl[ct], acc[rt][ct], 0, 0, 0);
        acc[rt][ct] = __builtin_amdgcn_mfma_f32_16x16x32_bf16(al, bh[ct], acc[rt][ct], 0, 0, 0);
      }
    }
    if (t + 1 < NT){
      __syncthreads();
      #pragma unroll
      for (int g = 0; g < 4; ++g){
        int idx = sar * LDR + ((sak + g * 4) ^ cA);
        float xs[4] = {pa[g].x, pa[g].y, pa[g].z, pa[g].w};
        u16x4 h, l;
        #pragma unroll
        for (int e = 0; e < 4; ++e){
          unsigned short hb_ = f2bf(xs[e]);
          h[e] = hb_; l[e] = f2bf(xs[e] - bf2f(hb_));
        }
        *(u16x4*)&Ah[idx] = h; *(u16x4*)&Al[idx] = l;
      }
      {
        int kx = sbk ^ cB;
        #pragma unroll
        for (int g = 0; g < 4; ++g){
          float xs[4] = {pb[g].x, pb[g].y, pb[g].z, pb[g].w};
          #pragma unroll
          for (int e = 0; e < 4; ++e){
            int n = sbn + g * 4 + e;
            unsigned short hb_ = f2bf(xs[e]);
            Bh[n * LDR + kx] = hb_;
            Bl[n * LDR + kx] = f2bf(xs[e] - bf2f(hb_));
          }
        }
      }
      __syncthreads();
    }
  }

  #pragma unroll
  for (int ct = 0; ct < 4; ++ct){
    int gc = n0 + wn0 + ct * 16 + rowb;
    float bv = bias[gc];
    #pragma unroll
    for (int rt = 0; rt < 4; ++rt){
      int gr0 = m0 + wm0 + rt * 16 + (lane >> 4) * 4;
      #pragma unroll
      for (int q = 0; q < 4; ++q){
        size_t off = (size_t)(gr0 + q) * N + gc;
        float v = acc[rt][ct][q] + bv;
        if (EPI == 1) v = fmaxf(v, 0.f);
        if (EPI == 2) v += resid[off];
        out[off] = v;
      }
    }
  }
}

// ---------------------------------------------------------------- attention v6 (MFMA flash)
// Swapped-QK flash attention on the matrix pipe (round-8 verified math).
// Round-9 change: 1024-thread blocks (16 waves) -> 4 waves/SIMD at the same
// 113 KB LDS (1 block/CU), and K/V staging runs in half as many blocks.
__global__ __launch_bounds__(1024) void attn_v6(
    const float* __restrict__ qkv, float* __restrict__ o)
{
  constexpr int LDK = 40;    // ushorts per K row (80 B, 16B-aligned)
  constexpr int LDV = 520;   // ushorts per Vt row
  __shared__ unsigned short Khi[512*LDK];   // 40 KB
  __shared__ unsigned short Klo[512*LDK];   // 40 KB
  __shared__ unsigned short Vt[32*LDV];     // 32.5 KB
  __shared__ float cbuf[16][16];

  const int tid = threadIdx.x;
  const int qc = blockIdx.x, h = blockIdx.y, b = blockIdx.z;
  const float* base = qkv + (size_t)b*1024*768;
  const int hoff = h*32;
  const float sc = 0.17677669529663687f;   // 1/sqrt(32)

  // ---- stage K (hi/lo bf16) and V^T (bf16), keys 0..511
  #pragma unroll
  for (int t = 0; t < 4; ++t){
    int i = tid + t*1024;
    int row = i >> 3, c4 = (i & 7) * 4;
    float4 kv = *(const float4*)&base[(size_t)row*768 + 256 + hoff + c4];
    float ks[4] = {kv.x, kv.y, kv.z, kv.w};
    u16x4 hk, lk;
    #pragma unroll
    for (int e = 0; e < 4; ++e){
      unsigned short hb_ = f2bf(ks[e]);
      hk[e] = hb_; lk[e] = f2bf(ks[e] - bf2f(hb_));
    }
    *(u16x4*)&Khi[row*LDK + c4] = hk;
    *(u16x4*)&Klo[row*LDK + c4] = lk;
    float4 vv = *(const float4*)&base[(size_t)row*768 + 512 + hoff + c4];
    float vs[4] = {vv.x, vv.y, vv.z, vv.w};
    #pragma unroll
    for (int e = 0; e < 4; ++e)
      Vt[(c4 + e)*LDV + row] = f2bf(vs[e]);
  }

  // ---- per-wave setup: wave wv owns q-rows q0w..q0w+15
  const int wv = tid >> 6, lane = tid & 63;
  const int g = lane >> 4, r = lane & 15;
  const int q0w = qc*256 + wv*16;

  short8 qh, ql;
  {
    const float* qp = &base[(size_t)(q0w + r)*768 + hoff + g*8];
    float4 a = *(const float4*)qp;
    float4 c = *(const float4*)(qp + 4);
    float xs[8] = {a.x*sc, a.y*sc, a.z*sc, a.w*sc, c.x*sc, c.y*sc, c.z*sc, c.w*sc};
    #pragma unroll
    for (int e = 0; e < 8; ++e){
      unsigned short hb_ = f2bf(xs[e]);
      qh[e] = (short)hb_;
      ql[e] = (short)f2bf(xs[e] - bf2f(hb_));
    }
  }
  __syncthreads();

  float m = -1e30f, l = 0.f;
  f32x4 O0 = {0.f,0.f,0.f,0.f}, O1 = {0.f,0.f,0.f,0.f};

  for (int st = 0; st < 16; ++st){
    int key0 = st*32 + (r >> 2)*8 + (r & 3);
    short8 ah0 = *(const short8*)&Khi[key0*LDK + g*8];
    short8 al0 = *(const short8*)&Klo[key0*LDK + g*8];
    short8 ah1 = *(const short8*)&Khi[(key0+4)*LDK + g*8];
    short8 al1 = *(const short8*)&Klo[(key0+4)*LDK + g*8];
    f32x4 s0 = {0.f,0.f,0.f,0.f}, s1 = {0.f,0.f,0.f,0.f};
    s0 = __builtin_amdgcn_mfma_f32_16x16x32_bf16(ah0, qh, s0, 0,0,0);
    s0 = __builtin_amdgcn_mfma_f32_16x16x32_bf16(ah0, ql, s0, 0,0,0);
    s0 = __builtin_amdgcn_mfma_f32_16x16x32_bf16(al0, qh, s0, 0,0,0);
    s1 = __builtin_amdgcn_mfma_f32_16x16x32_bf16(ah1, qh, s1, 0,0,0);
    s1 = __builtin_amdgcn_mfma_f32_16x16x32_bf16(ah1, ql, s1, 0,0,0);
    s1 = __builtin_amdgcn_mfma_f32_16x16x32_bf16(al1, qh, s1, 0,0,0);
    float pv[8] = {s0[0],s0[1],s0[2],s0[3], s1[0],s1[1],s1[2],s1[3]};
    float tm = pv[0];
    #pragma unroll
    for (int j = 1; j < 8; ++j) tm = fmaxf(tm, pv[j]);
    tm = fmaxf(tm, __shfl_xor(tm, 16));
    tm = fmaxf(tm, __shfl_xor(tm, 32));
    float mn = fmaxf(m, tm);
    float ts = 0.f;
    #pragma unroll
    for (int j = 0; j < 8; ++j){ pv[j] = __expf(pv[j] - mn); ts += pv[j]; }
    ts += __shfl_xor(ts, 16);
    ts += __shfl_xor(ts, 32);
    if (__any(mn > m)){
      float corr = __expf(m - mn);
      if (lane < 16) cbuf[wv][lane] = corr;
      asm volatile("s_waitcnt lgkmcnt(0)" ::: "memory");
      f32x4 cf = *(const f32x4*)&cbuf[wv][g*4];
      #pragma unroll
      for (int j = 0; j < 4; ++j){ O0[j] *= cf[j]; O1[j] *= cf[j]; }
      l *= corr;
      m = mn;
    }
    l += ts;
    short8 pa;
    #pragma unroll
    for (int j = 0; j < 8; ++j) pa[j] = (short)f2bf(pv[j]);
    short8 v0 = *(const short8*)&Vt[(size_t)r*LDV + st*32 + g*8];
    short8 v1 = *(const short8*)&Vt[(size_t)(r+16)*LDV + st*32 + g*8];
    O0 = __builtin_amdgcn_mfma_f32_16x16x32_bf16(pa, v0, O0, 0,0,0);
    O1 = __builtin_amdgcn_mfma_f32_16x16x32_bf16(pa, v1, O1, 0,0,0);
  }

  // ---- self-attend tile (targets only): diagonal-masked, K/V from global
  if (qc >= 2){
    const float* kp = &base[(size_t)(q0w + r)*768 + 256 + hoff + g*8];
    float4 a = *(const float4*)kp;
    float4 c = *(const float4*)(kp + 4);
    float xs[8] = {a.x, a.y, a.z, a.w, c.x, c.y, c.z, c.w};
    short8 ah, al;
    #pragma unroll
    for (int e = 0; e < 8; ++e){
      unsigned short hb_ = f2bf(xs[e]);
      ah[e] = (short)hb_;
      al[e] = (short)f2bf(xs[e] - bf2f(hb_));
    }
    f32x4 s = {0.f,0.f,0.f,0.f};
    s = __builtin_amdgcn_mfma_f32_16x16x32_bf16(ah, qh, s, 0,0,0);
    s = __builtin_amdgcn_mfma_f32_16x16x32_bf16(ah, ql, s, 0,0,0);
    s = __builtin_amdgcn_mfma_f32_16x16x32_bf16(al, qh, s, 0,0,0);
    float pv[8] = {0.f,0.f,0.f,0.f,0.f,0.f,0.f,0.f};
    float tm = -1e30f;
    #pragma unroll
    for (int j = 0; j < 4; ++j){
      bool al_ = (g*4 + j) == r;
      tm = fmaxf(tm, al_ ? s[j] : -1e30f);
    }
    tm = fmaxf(tm, __shfl_xor(tm, 16));
    tm = fmaxf(tm, __shfl_xor(tm, 32));
    float mn = fmaxf(m, tm);
    float ts = 0.f;
    #pragma unroll
    for (int j = 0; j < 4; ++j){
      bool al_ = (g*4 + j) == r;
      pv[j] = al_ ? __expf(s[j] - mn) : 0.f;
      ts += pv[j];
    }
    ts += __shfl_xor(ts, 16);
    ts += __shfl_xor(ts, 32);
    if (__any(mn > m)){
      float corr = __expf(m - mn);
      if (lane < 16) cbuf[wv][lane] = corr;
      asm volatile("s_waitcnt lgkmcnt(0)" ::: "memory");
      f32x4 cf = *(const f32x4*)&cbuf[wv][g*4];
      #pragma unroll
      for (int j = 0; j < 4; ++j){ O0[j] *= cf[j]; O1[j] *= cf[j]; }
      l *= corr;
      m = mn;
    }
    l += ts;
    short8 pa, v0, v1;
    #pragma unroll
    for (int j = 0; j < 8; ++j) pa[j] = (short)f2bf(pv[j]);
    #pragma unroll
    for (int j = 0; j < 4; ++j){
      const float* vp = &base[(size_t)(q0w + g*4 + j)*768 + 512 + hoff];
      v0[j] = (short)f2bf(vp[r]);
      v1[j] = (short)f2bf(vp[r + 16]);
      v0[j+4] = 0; v1[j+4] = 0;
    }
    O0 = __builtin_amdgcn_mfma_f32_16x16x32_bf16(pa, v0, O0, 0,0,0);
    O1 = __builtin_amdgcn_mfma_f32_16x16x32_bf16(pa, v1, O1, 0,0,0);
  }

  // ---- normalize and store
  float inv = 1.f / l;
  if (lane < 16) cbuf[wv][lane] = inv;
  asm volatile("s_waitcnt lgkmcnt(0)" ::: "memory");
  f32x4 iv = *(const f32x4*)&cbuf[wv][g*4];
  float* op = o + ((size_t)b*1024 + q0w + g*4)*256 + hoff;
  #pragma unroll
  for (int j = 0; j < 4; ++j){
    op[(size_t)j*256 + r]      = O0[j] * iv[j];
    op[(size_t)j*256 + r + 16] = O1[j] * iv[j];
  }
}

// ---------------------------------------------------------------- launch
extern "C" void kernel_launch(void* const* d_in, const int* in_sizes, int n_in,
                              void* d_out, int out_size, void* d_ws, size_t ws_size,
                              hipStream_t stream)
{
  (void)in_sizes; (void)n_in; (void)out_size;
  const float* xc   = (const float*)d_in[0];
  const float* yc   = (const float*)d_in[1];
  const float* xt   = (const float*)d_in[2];
  const float* eW1  = (const float*)d_in[3];
  const float* eb1  = (const float*)d_in[4];
  const float* eW2  = (const float*)d_in[5];
  const float* eb2  = (const float*)d_in[6];
  const float* Wqkv = (const float*)d_in[7];
  const float* bqkv = (const float*)d_in[8];
  const float* Wo   = (const float*)d_in[9];
  const float* bo   = (const float*)d_in[10];
  const float* ln1g = (const float*)d_in[11];
  const float* ln1b = (const float*)d_in[12];
  const float* ln2g = (const float*)d_in[13];
  const float* ln2b = (const float*)d_in[14];
  const float* Wff1 = (const float*)d_in[15];
  const float* bff1 = (const float*)d_in[16];
  const float* Wff2 = (const float*)d_in[17];
  const float* bff2 = (const float*)d_in[18];

  float* zf = (float*)d_out;            // residual stream [8][1024][256] f32 = 8 MB
  char* ws = (char*)d_ws;
  float* hb      = (float*)(ws);                        // 8 MB (LN out / attn out)
  float* scratch = (float*)(ws + (size_t)8*1024*1024);  // qkv / ffh

  const bool bigws = (ws_size == 0) || (ws_size >= (size_t)33*1024*1024);

  // encoder: stage1 (K=10, vector) -> hb, then MFMA GEMM for the 256x256 layer
  encoder_s1<<<8192, 256, 0, stream>>>(xc, yc, xt, eW1, eb1, hb);
  gemm_mfma<0><<<dim3(2,64), 256, 0, stream>>>(hb, eW2, eb2, nullptr, zf, 256, 256);

  for (int l=0; l<6; l++){
    const float* Wq = Wqkv + (size_t)l*256*768;
    const float* Wl = Wo   + (size_t)l*256*256;
    const float* W1 = Wff1 + (size_t)l*256*1024;
    const float* W2 = Wff2 + (size_t)l*1024*256;

    ln_v2<<<2048, 256, 0, stream>>>(zf, ln1g+l*256, ln1b+l*256, hb);
    if (bigws){
      gemm_mfma<0><<<dim3(6,64), 256, 0, stream>>>(hb, Wq, bqkv+l*768,
                                                   nullptr, scratch, 768, 256);
      attn_v6<<<dim3(4,8,8), 1024, 0, stream>>>(scratch, hb);
    } else {
      for (int c=0; c<4; c++){           // 2 batches per chunk (6 MB scratch)
        float* hrows = hb + (size_t)c*2048*256;
        gemm_mfma<0><<<dim3(6,16), 256, 0, stream>>>(hrows, Wq, bqkv+l*768,
                                                     nullptr, scratch, 768, 256);
        attn_v6<<<dim3(4,8,2), 1024, 0, stream>>>(scratch, hrows);
      }
    }
    gemm_mfma<2><<<dim3(2,64), 256, 0, stream>>>(hb, Wl, bo+l*256, zf, zf, 256, 256);

    ln_v2<<<2048, 256, 0, stream>>>(zf, ln2g+l*256, ln2b+l*256, hb);
    if (bigws){
      for (int c=0; c<2; c++){           // 4-batch FF chunks (ffh 16 MB scratch)
        float* hrows = hb + (size_t)c*4096*256;
        float* zrows = zf + (size_t)c*4096*256;
        gemm_mfma<1><<<dim3(8,32), 256, 0, stream>>>(hrows, W1, bff1+l*1024,
                                                     nullptr, scratch, 1024, 256);
        gemm_mfma<2><<<dim3(2,32), 256, 0, stream>>>(scratch, W2, bff2+l*256,
                                                     zrows, zrows, 256, 1024);
      }
    } else {
      for (int c=0; c<4; c++){           // 2-batch FF chunks (ffh 8 MB scratch)
        float* hrows = hb + (size_t)c*2048*256;
        float* zrows = zf + (size_t)c*2048*256;
        gemm_mfma<1><<<dim3(8,16), 256, 0, stream>>>(hrows, W1, bff1+l*1024,
                                                     nullptr, scratch, 1024, 256);
        gemm_mfma<2><<<dim3(2,16), 256, 0, stream>>>(scratch, W2, bff2+l*256,
                                                     zrows, zrows, 256, 1024);
      }
    }
  }
}

// Round 10
// 846.152 us; speedup vs baseline: 20.2083x; 1.5966x over previous
//
#include <hip/hip_runtime.h>

typedef short short8 __attribute__((ext_vector_type(8)));
typedef float f32x4 __attribute__((ext_vector_type(4)));
typedef unsigned short u16x4 __attribute__((ext_vector_type(4)));

// f32 -> bf16 bits (round-to-nearest-even; finite inputs only)
__device__ __forceinline__ unsigned short f2bf(float x){
  unsigned int u = __float_as_uint(x);
  u = u + 0x7FFFu + ((u >> 16) & 1u);
  return (unsigned short)(u >> 16);
}
__device__ __forceinline__ float bf2f(unsigned short h){
  return __uint_as_float(((unsigned int)h) << 16);
}
// truncation split: hi = trunc16(x) (exact same-sign), lo = RNE(x - hi).
// |x - hi - lo| <= 2^-17 |x|; ~7 VALU vs ~10 for double-RNE split.
__device__ __forceinline__ void tsplit(float x, unsigned short& h, unsigned short& l){
  unsigned int u = __float_as_uint(x);
  h = (unsigned short)(u >> 16);
  l = f2bf(x - __uint_as_float(u & 0xFFFF0000u));
}

// ---------------------------------------------------------------- weight split conv
// Converts up to two f32 matrices into bf16 hi/lo planes (trunc split).
// Sizes n0/n1 in float4 units. Run once per layer: B-operands are then
// staged in gemm as pure u16 copies (round-9 lesson: per-block re-conversion
// of weights was ~60% of gemm cycles; ff2 was 54us at 4% MfmaUtil).
__global__ __launch_bounds__(256) void conv2(
    const float4* __restrict__ S0, int n0, u16x4* __restrict__ D0h, u16x4* __restrict__ D0l,
    const float4* __restrict__ S1, int n1, u16x4* __restrict__ D1h, u16x4* __restrict__ D1l)
{
  int i = blockIdx.x*256 + threadIdx.x;
  const float4* S; u16x4 *Dh, *Dl;
  if (i < n0){ S = S0 + i; Dh = D0h + i; Dl = D0l + i; }
  else { i -= n0; if (i >= n1) return; S = S1 + i; Dh = D1h + i; Dl = D1l + i; }
  float4 v = *S;
  float xs[4] = {v.x, v.y, v.z, v.w};
  u16x4 h, l;
  #pragma unroll
  for (int e = 0; e < 4; ++e){ unsigned short hh, ll; tsplit(xs[e], hh, ll); h[e]=hh; l[e]=ll; }
  *Dh = h; *Dl = l;
}

// ---------------------------------------------------------------- encoder stage 1
__global__ __launch_bounds__(256) void encoder_s1(
    const float* __restrict__ xc, const float* __restrict__ yc, const float* __restrict__ xt,
    const float* __restrict__ W1, const float* __restrict__ b1,
    float* __restrict__ hid)
{
  __shared__ float zin[10];
  int blk = blockIdx.x; int b = blk>>10; int t = blk & 1023;
  int tid = threadIdx.x;
  if (tid < 10){
    float v;
    if (tid < 8)      v = (t<512) ? xc[((size_t)b*512+t)*8+tid] : xt[((size_t)b*512+(t-512))*8+tid];
    else if (tid==8)  v = (t<512) ? yc[(size_t)b*512+t] : 0.f;
    else              v = (t<512) ? 0.f : 1.f;
    zin[tid]=v;
  }
  __syncthreads();
  float s = b1[tid];
  #pragma unroll
  for (int i=0;i<10;i++) s += zin[i]*W1[i*256+tid];
  hid[(size_t)blk*256 + tid] = fmaxf(s, 0.f);
}

// ---------------------------------------------------------------- layernorm v2
__global__ __launch_bounds__(256) void ln_v2(const float* __restrict__ z,
    const float* __restrict__ g, const float* __restrict__ be, float* __restrict__ h)
{
  const int row = blockIdx.x*4 + (threadIdx.x>>6);
  const int lane = threadIdx.x & 63;
  float4 x = *(const float4*)&z[(size_t)row*256 + lane*4];
  float s = (x.x+x.y)+(x.z+x.w);
  #pragma unroll
  for (int off=32; off; off>>=1) s += __shfl_xor(s, off);
  float mu = s * (1.f/256.f);
  float dx = x.x-mu, dy = x.y-mu, dz = x.z-mu, dw = x.w-mu;
  float v = (dx*dx+dy*dy)+(dz*dz+dw*dw);
  #pragma unroll
  for (int off=32; off; off>>=1) v += __shfl_xor(v, off);
  float r = rsqrtf(v*(1.f/256.f) + 1e-5f);
  float4 gv = *(const float4*)&g[lane*4];
  float4 bv = *(const float4*)&be[lane*4];
  float4 o;
  o.x = dx*r*gv.x + bv.x; o.y = dy*r*gv.y + bv.y;
  o.z = dz*r*gv.z + bv.z; o.w = dw*r*gv.w + bv.w;
  *(float4*)&h[(size_t)row*256 + lane*4] = o;
}

// ---------------------------------------------------------------- gemm_mfma v3
// out = EPI(A @ B + bias). 128x128 block, 4 waves, split-bf16 MFMA.
// APRE: 0 = A f32 (trunc-split in kernel, 3-term MFMA)
//       1 = A bf16 plane (copy-stage, 2-term MFMA: ah*bh + ah*bl)
// BPRE: 0 = B f32 (split in kernel)   1 = B pre-split hi/lo planes (copy)
// EPI : 0 plain f32 ; 1 relu f32 ; 2 +resid f32 ; 3 relu -> bf16 out
// Frag layouts HW-verified rounds 7-9. No launch_bounds min-waves (R4/R5).
template<int APRE, int BPRE, int EPI>
__global__ __launch_bounds__(256) void gemm_mfma(
    const float* __restrict__ Af, const unsigned short* __restrict__ Ab,
    const float* __restrict__ Bf,
    const unsigned short* __restrict__ Bhg, const unsigned short* __restrict__ Blg,
    const float* __restrict__ bias, const float* __restrict__ resid,
    float* __restrict__ outf, unsigned short* __restrict__ outb,
    int N, int K)
{
  constexpr int LDR = 40;
  __shared__ unsigned short Ah[128*LDR];
  __shared__ unsigned short Al[(APRE==0)?(128*LDR):8];
  __shared__ unsigned short Bh[128*LDR], Bl[128*LDR];

  const int tid = threadIdx.x;
  const int lane = tid & 63, wv = tid >> 6;
  const int wm0 = (wv >> 1) * 64, wn0 = (wv & 1) * 64;
  const int m0 = blockIdx.y * 128, n0 = blockIdx.x * 128;

  const int sar = tid >> 1, sak = (tid & 1) * 16;
  const int sbk = tid >> 3, sbn = (tid & 7) * 16;
  const int cA = ((sar >> 3) & 3) << 3;
  const int cB = ((sbn >> 4) & 3) << 3;

  const float* Apf = nullptr; const unsigned short* Apb = nullptr;
  if constexpr (APRE==0) Apf = Af + (size_t)(m0 + sar) * K + sak;
  else                   Apb = Ab + (size_t)(m0 + sar) * K + sak;
  const float* Bpf = nullptr; const unsigned short *Bph = nullptr, *Bpl = nullptr;
  if constexpr (BPRE==0) Bpf = Bf + (size_t)sbk * N + n0 + sbn;
  else { Bph = Bhg + (size_t)sbk * N + n0 + sbn; Bpl = Blg + (size_t)sbk * N + n0 + sbn; }

  const int rowb = lane & 15, kb = (lane >> 4) * 8;

  f32x4 acc[4][4] = {};
  float4 pa[4], pb[4];
  u16x4 qa[4], qbh[4], qbl[4];
  const int NT = K / 32;

  // ---- load tile t into prefetch regs
  auto LOADT = [&](int t){
    #pragma unroll
    for (int g = 0; g < 4; ++g){
      if constexpr (APRE==0) pa[g] = *(const float4*)&Apf[t*32 + g*4];
      else                   qa[g] = *(const u16x4*)&Apb[t*32 + g*4];
    }
    #pragma unroll
    for (int g = 0; g < 4; ++g){
      if constexpr (BPRE==0) pb[g] = *(const float4*)&Bpf[(size_t)t*32*N + g*4];
      else {
        qbh[g] = *(const u16x4*)&Bph[(size_t)t*32*N + g*4];
        qbl[g] = *(const u16x4*)&Bpl[(size_t)t*32*N + g*4];
      }
    }
  };
  // ---- stage prefetch regs into LDS
  auto STAGE = [&](){
    #pragma unroll
    for (int g = 0; g < 4; ++g){
      int idx = sar * LDR + ((sak + g * 4) ^ cA);
      if constexpr (APRE==0){
        float xs[4] = {pa[g].x, pa[g].y, pa[g].z, pa[g].w};
        u16x4 h, l;
        #pragma unroll
        for (int e = 0; e < 4; ++e){ unsigned short hh, ll; tsplit(xs[e], hh, ll); h[e]=hh; l[e]=ll; }
        *(u16x4*)&Ah[idx] = h; *(u16x4*)&Al[idx] = l;
      } else {
        *(u16x4*)&Ah[idx] = qa[g];
      }
    }
    int kx = sbk ^ cB;
    #pragma unroll
    for (int g = 0; g < 4; ++g){
      if constexpr (BPRE==0){
        float xs[4] = {pb[g].x, pb[g].y, pb[g].z, pb[g].w};
        #pragma unroll
        for (int e = 0; e < 4; ++e){
          int n = sbn + g * 4 + e;
          unsigned short hh, ll; tsplit(xs[e], hh, ll);
          Bh[n * LDR + kx] = hh; Bl[n * LDR + kx] = ll;
        }
      } else {
        #pragma unroll
        for (int e = 0; e < 4; ++e){
          int n = sbn + g * 4 + e;
          Bh[n * LDR + kx] = qbh[g][e]; Bl[n * LDR + kx] = qbl[g][e];
        }
      }
    }
  };

  LOADT(0);
  STAGE();
  __syncthreads();

  for (int t = 0; t < NT; ++t){
    if (t + 1 < NT) LOADT(t + 1);
    short8 bh[4], bl[4];
    #pragma unroll
    for (int ct = 0; ct < 4; ++ct){
      int n = wn0 + ct * 16 + rowb;
      int idx = n * LDR + (kb ^ (((n >> 4) & 3) << 3));
      bh[ct] = *(const short8*)&Bh[idx];
      bl[ct] = *(const short8*)&Bl[idx];
    }
    #pragma unroll
    for (int rt = 0; rt < 4; ++rt){
      int r = wm0 + rt * 16 + rowb;
      int idx = r * LDR + (kb ^ (((r >> 3) & 3) << 3));
      short8 ah = *(const short8*)&Ah[idx];
      #pragma unroll
      for (int ct = 0; ct < 4; ++ct){
        acc[rt][ct] = __builtin_amdgcn_mfma_f32_16x16x32_bf16(ah, bh[ct], acc[rt][ct], 0, 0, 0);
        acc[rt][ct] = __builtin_amdgcn_mfma_f32_16x16x32_bf16(ah, bl[ct], acc[rt][ct], 0, 0, 0);
      }
      if constexpr (APRE==0){
        short8 al = *(const short8*)&Al[idx];
        #pragma unroll
        for (int ct = 0; ct < 4; ++ct)
          acc[rt][ct] = __builtin_amdgcn_mfma_f32_16x16x32_bf16(al, bh[ct], acc[rt][ct], 0, 0, 0);
      }
    }
    if (t + 1 < NT){
      __syncthreads();
      STAGE();
      __syncthreads();
    }
  }

  // epilogue: C/D layout col=lane&15, row=(lane>>4)*4+q
  #pragma unroll
  for (int ct = 0; ct < 4; ++ct){
    int gc = n0 + wn0 + ct * 16 + rowb;
    float bv = bias[gc];
    #pragma unroll
    for (int rt = 0; rt < 4; ++rt){
      int gr0 = m0 + wm0 + rt * 16 + (lane >> 4) * 4;
      #pragma unroll
      for (int q = 0; q < 4; ++q){
        size_t off = (size_t)(gr0 + q) * N + gc;
        float v = acc[rt][ct][q] + bv;
        if constexpr (EPI == 1) v = fmaxf(v, 0.f);
        if constexpr (EPI == 2) v += resid[off];
        if constexpr (EPI == 3) outb[off] = f2bf(fmaxf(v, 0.f));
        else                    outf[off] = v;
      }
    }
  }
}

// ---------------------------------------------------------------- attention v6 (MFMA flash)
// (unchanged from round 9 — verified) 1024-thread blocks, 16 waves.
__global__ __launch_bounds__(1024) void attn_v6(
    const float* __restrict__ qkv, float* __restrict__ o)
{
  constexpr int LDK = 40;
  constexpr int LDV = 520;
  __shared__ unsigned short Khi[512*LDK];
  __shared__ unsigned short Klo[512*LDK];
  __shared__ unsigned short Vt[32*LDV];
  __shared__ float cbuf[16][16];

  const int tid = threadIdx.x;
  const int qc = blockIdx.x, h = blockIdx.y, b = blockIdx.z;
  const float* base = qkv + (size_t)b*1024*768;
  const int hoff = h*32;
  const float sc = 0.17677669529663687f;

  #pragma unroll
  for (int t = 0; t < 4; ++t){
    int i = tid + t*1024;
    int row = i >> 3, c4 = (i & 7) * 4;
    float4 kv = *(const float4*)&base[(size_t)row*768 + 256 + hoff + c4];
    float ks[4] = {kv.x, kv.y, kv.z, kv.w};
    u16x4 hk, lk;
    #pragma unroll
    for (int e = 0; e < 4; ++e){
      unsigned short hb_ = f2bf(ks[e]);
      hk[e] = hb_; lk[e] = f2bf(ks[e] - bf2f(hb_));
    }
    *(u16x4*)&Khi[row*LDK + c4] = hk;
    *(u16x4*)&Klo[row*LDK + c4] = lk;
    float4 vv = *(const float4*)&base[(size_t)row*768 + 512 + hoff + c4];
    float vs[4] = {vv.x, vv.y, vv.z, vv.w};
    #pragma unroll
    for (int e = 0; e < 4; ++e)
      Vt[(c4 + e)*LDV + row] = f2bf(vs[e]);
  }

  const int wv = tid >> 6, lane = tid & 63;
  const int g = lane >> 4, r = lane & 15;
  const int q0w = qc*256 + wv*16;

  short8 qh, ql;
  {
    const float* qp = &base[(size_t)(q0w + r)*768 + hoff + g*8];
    float4 a = *(const float4*)qp;
    float4 c = *(const float4*)(qp + 4);
    float xs[8] = {a.x*sc, a.y*sc, a.z*sc, a.w*sc, c.x*sc, c.y*sc, c.z*sc, c.w*sc};
    #pragma unroll
    for (int e = 0; e < 8; ++e){
      unsigned short hb_ = f2bf(xs[e]);
      qh[e] = (short)hb_;
      ql[e] = (short)f2bf(xs[e] - bf2f(hb_));
    }
  }
  __syncthreads();

  float m = -1e30f, l = 0.f;
  f32x4 O0 = {0.f,0.f,0.f,0.f}, O1 = {0.f,0.f,0.f,0.f};

  for (int st = 0; st < 16; ++st){
    int key0 = st*32 + (r >> 2)*8 + (r & 3);
    short8 ah0 = *(const short8*)&Khi[key0*LDK + g*8];
    short8 al0 = *(const short8*)&Klo[key0*LDK + g*8];
    short8 ah1 = *(const short8*)&Khi[(key0+4)*LDK + g*8];
    short8 al1 = *(const short8*)&Klo[(key0+4)*LDK + g*8];
    f32x4 s0 = {0.f,0.f,0.f,0.f}, s1 = {0.f,0.f,0.f,0.f};
    s0 = __builtin_amdgcn_mfma_f32_16x16x32_bf16(ah0, qh, s0, 0,0,0);
    s0 = __builtin_amdgcn_mfma_f32_16x16x32_bf16(ah0, ql, s0, 0,0,0);
    s0 = __builtin_amdgcn_mfma_f32_16x16x32_bf16(al0, qh, s0, 0,0,0);
    s1 = __builtin_amdgcn_mfma_f32_16x16x32_bf16(ah1, qh, s1, 0,0,0);
    s1 = __builtin_amdgcn_mfma_f32_16x16x32_bf16(ah1, ql, s1, 0,0,0);
    s1 = __builtin_amdgcn_mfma_f32_16x16x32_bf16(al1, qh, s1, 0,0,0);
    float pv[8] = {s0[0],s0[1],s0[2],s0[3], s1[0],s1[1],s1[2],s1[3]};
    float tm = pv[0];
    #pragma unroll
    for (int j = 1; j < 8; ++j) tm = fmaxf(tm, pv[j]);
    tm = fmaxf(tm, __shfl_xor(tm, 16));
    tm = fmaxf(tm, __shfl_xor(tm, 32));
    float mn = fmaxf(m, tm);
    float ts = 0.f;
    #pragma unroll
    for (int j = 0; j < 8; ++j){ pv[j] = __expf(pv[j] - mn); ts += pv[j]; }
    ts += __shfl_xor(ts, 16);
    ts += __shfl_xor(ts, 32);
    if (__any(mn > m)){
      float corr = __expf(m - mn);
      if (lane < 16) cbuf[wv][lane] = corr;
      asm volatile("s_waitcnt lgkmcnt(0)" ::: "memory");
      f32x4 cf = *(const f32x4*)&cbuf[wv][g*4];
      #pragma unroll
      for (int j = 0; j < 4; ++j){ O0[j] *= cf[j]; O1[j] *= cf[j]; }
      l *= corr;
      m = mn;
    }
    l += ts;
    short8 pa;
    #pragma unroll
    for (int j = 0; j < 8; ++j) pa[j] = (short)f2bf(pv[j]);
    short8 v0 = *(const short8*)&Vt[(size_t)r*LDV + st*32 + g*8];
    short8 v1 = *(const short8*)&Vt[(size_t)(r+16)*LDV + st*32 + g*8];
    O0 = __builtin_amdgcn_mfma_f32_16x16x32_bf16(pa, v0, O0, 0,0,0);
    O1 = __builtin_amdgcn_mfma_f32_16x16x32_bf16(pa, v1, O1, 0,0,0);
  }

  if (qc >= 2){
    const float* kp = &base[(size_t)(q0w + r)*768 + 256 + hoff + g*8];
    float4 a = *(const float4*)kp;
    float4 c = *(const float4*)(kp + 4);
    float xs[8] = {a.x, a.y, a.z, a.w, c.x, c.y, c.z, c.w};
    short8 ah, al;
    #pragma unroll
    for (int e = 0; e < 8; ++e){
      unsigned short hb_ = f2bf(xs[e]);
      ah[e] = (short)hb_;
      al[e] = (short)f2bf(xs[e] - bf2f(hb_));
    }
    f32x4 s = {0.f,0.f,0.f,0.f};
    s = __builtin_amdgcn_mfma_f32_16x16x32_bf16(ah, qh, s, 0,0,0);
    s = __builtin_amdgcn_mfma_f32_16x16x32_bf16(ah, ql, s, 0,0,0);
    s = __builtin_amdgcn_mfma_f32_16x16x32_bf16(al, qh, s, 0,0,0);
    float pv[8] = {0.f,0.f,0.f,0.f,0.f,0.f,0.f,0.f};
    float tm = -1e30f;
    #pragma unroll
    for (int j = 0; j < 4; ++j){
      bool al_ = (g*4 + j) == r;
      tm = fmaxf(tm, al_ ? s[j] : -1e30f);
    }
    tm = fmaxf(tm, __shfl_xor(tm, 16));
    tm = fmaxf(tm, __shfl_xor(tm, 32));
    float mn = fmaxf(m, tm);
    float ts = 0.f;
    #pragma unroll
    for (int j = 0; j < 4; ++j){
      bool al_ = (g*4 + j) == r;
      pv[j] = al_ ? __expf(s[j] - mn) : 0.f;
      ts += pv[j];
    }
    ts += __shfl_xor(ts, 16);
    ts += __shfl_xor(ts, 32);
    if (__any(mn > m)){
      float corr = __expf(m - mn);
      if (lane < 16) cbuf[wv][lane] = corr;
      asm volatile("s_waitcnt lgkmcnt(0)" ::: "memory");
      f32x4 cf = *(const f32x4*)&cbuf[wv][g*4];
      #pragma unroll
      for (int j = 0; j < 4; ++j){ O0[j] *= cf[j]; O1[j] *= cf[j]; }
      l *= corr;
      m = mn;
    }
    l += ts;
    short8 pa, v0, v1;
    #pragma unroll
    for (int j = 0; j < 8; ++j) pa[j] = (short)f2bf(pv[j]);
    #pragma unroll
    for (int j = 0; j < 4; ++j){
      const float* vp = &base[(size_t)(q0w + g*4 + j)*768 + 512 + hoff];
      v0[j] = (short)f2bf(vp[r]);
      v1[j] = (short)f2bf(vp[r + 16]);
      v0[j+4] = 0; v1[j+4] = 0;
    }
    O0 = __builtin_amdgcn_mfma_f32_16x16x32_bf16(pa, v0, O0, 0,0,0);
    O1 = __builtin_amdgcn_mfma_f32_16x16x32_bf16(pa, v1, O1, 0,0,0);
  }

  float inv = 1.f / l;
  if (lane < 16) cbuf[wv][lane] = inv;
  asm volatile("s_waitcnt lgkmcnt(0)" ::: "memory");
  f32x4 iv = *(const f32x4*)&cbuf[wv][g*4];
  float* op = o + ((size_t)b*1024 + q0w + g*4)*256 + hoff;
  #pragma unroll
  for (int j = 0; j < 4; ++j){
    op[(size_t)j*256 + r]      = O0[j] * iv[j];
    op[(size_t)j*256 + r + 16] = O1[j] * iv[j];
  }
}

// ---------------------------------------------------------------- launch
extern "C" void kernel_launch(void* const* d_in, const int* in_sizes, int n_in,
                              void* d_out, int out_size, void* d_ws, size_t ws_size,
                              hipStream_t stream)
{
  (void)in_sizes; (void)n_in; (void)out_size;
  const float* xc   = (const float*)d_in[0];
  const float* yc   = (const float*)d_in[1];
  const float* xt   = (const float*)d_in[2];
  const float* eW1  = (const float*)d_in[3];
  const float* eb1  = (const float*)d_in[4];
  const float* eW2  = (const float*)d_in[5];
  const float* eb2  = (const float*)d_in[6];
  const float* Wqkv = (const float*)d_in[7];
  const float* bqkv = (const float*)d_in[8];
  const float* Wo   = (const float*)d_in[9];
  const float* bo   = (const float*)d_in[10];
  const float* ln1g = (const float*)d_in[11];
  const float* ln1b = (const float*)d_in[12];
  const float* ln2g = (const float*)d_in[13];
  const float* ln2b = (const float*)d_in[14];
  const float* Wff1 = (const float*)d_in[15];
  const float* bff1 = (const float*)d_in[16];
  const float* Wff2 = (const float*)d_in[17];
  const float* bff2 = (const float*)d_in[18];

  float* zf = (float*)d_out;            // residual stream [8][1024][256] f32 = 8 MB
  char* ws = (char*)d_ws;
  float* hb      = (float*)(ws);                        // 8 MiB (LN out / attn out)
  float* scratch = (float*)(ws + (size_t)8*1024*1024);  // qkv f32 (24 MiB) / ffh bf16 (16 MiB)

  const bool bigws = (ws_size == 0) || (ws_size >= (size_t)33*1024*1024);

  if (bigws){
    // weight-split regions (bigws guarantees ws >= 33 MiB):
    //   wsA = ws+32MiB, 1 MiB exactly: [qkvh|qkvl|woh|wol]  (also enc split pre-loop)
    //   wsB = ws+24MiB, 2 MiB: [w1h|w1l|w2h|w2l] -- inside qkv scratch tail; written
    //         only AFTER attn (qkv dead), disjoint from ffh [ws+8,ws+24).
    unsigned short* wsA = (unsigned short*)(ws + (size_t)32*1024*1024);
    unsigned short* wsB = (unsigned short*)(ws + (size_t)24*1024*1024);
    unsigned short* qkvh = wsA,            * qkvl = wsA + 196608;
    unsigned short* woh  = wsA + 393216,   * wol  = wsA + 458752;
    unsigned short* w1h  = wsB,            * w1l  = wsB + 262144;
    unsigned short* w2h  = wsB + 524288,   * w2l  = wsB + 786432;
    unsigned short* ffh_b = (unsigned short*)scratch;   // [8192][1024] bf16, 16 MiB

    // encoder: split enc_W2 (reuses wsA before the loop), s1, MFMA gemm
    conv2<<<64, 256, 0, stream>>>((const float4*)eW2, 16384, (u16x4*)wsA, (u16x4*)(wsA+65536),
                                  nullptr, 0, nullptr, nullptr);
    encoder_s1<<<8192, 256, 0, stream>>>(xc, yc, xt, eW1, eb1, hb);
    gemm_mfma<0,1,0><<<dim3(2,64), 256, 0, stream>>>(hb, nullptr, nullptr, wsA, wsA+65536,
                                                     eb2, nullptr, zf, nullptr, 256, 256);

    for (int l=0; l<6; l++){
      const float* Wq = Wqkv + (size_t)l*256*768;
      const float* Wl = Wo   + (size_t)l*256*256;
      const float* W1 = Wff1 + (size_t)l*256*1024;
      const float* W2 = Wff2 + (size_t)l*1024*256;

      conv2<<<256, 256, 0, stream>>>((const float4*)Wq, 49152, (u16x4*)qkvh, (u16x4*)qkvl,
                                     (const float4*)Wl, 16384, (u16x4*)woh,  (u16x4*)wol);
      ln_v2<<<2048, 256, 0, stream>>>(zf, ln1g+l*256, ln1b+l*256, hb);
      gemm_mfma<0,1,0><<<dim3(6,64), 256, 0, stream>>>(hb, nullptr, nullptr, qkvh, qkvl,
                                                       bqkv+l*768, nullptr, scratch, nullptr, 768, 256);
      attn_v6<<<dim3(4,8,8), 1024, 0, stream>>>(scratch, hb);
      // qkv scratch now dead -> safe to write W1/W2 splits into its tail
      conv2<<<512, 256, 0, stream>>>((const float4*)W1, 65536, (u16x4*)w1h, (u16x4*)w1l,
                                     (const float4*)W2, 65536, (u16x4*)w2h, (u16x4*)w2l);
      gemm_mfma<0,1,2><<<dim3(2,64), 256, 0, stream>>>(hb, nullptr, nullptr, woh, wol,
                                                       bo+l*256, zf, zf, nullptr, 256, 256);
      ln_v2<<<2048, 256, 0, stream>>>(zf, ln2g+l*256, ln2b+l*256, hb);
      // FF, full batch (ffh bf16 halves the footprint -> no chunking):
      gemm_mfma<0,1,3><<<dim3(8,64), 256, 0, stream>>>(hb, nullptr, nullptr, w1h, w1l,
                                                       bff1+l*1024, nullptr, nullptr, ffh_b, 1024, 256);
      gemm_mfma<1,1,2><<<dim3(2,64), 256, 0, stream>>>(nullptr, ffh_b, nullptr, w2h, w2l,
                                                       bff2+l*256, zf, zf, nullptr, 256, 1024);
    }
  } else {
    // fallback: in-kernel conversion (round-9 behavior), chunked scratch
    encoder_s1<<<8192, 256, 0, stream>>>(xc, yc, xt, eW1, eb1, hb);
    gemm_mfma<0,0,0><<<dim3(2,64), 256, 0, stream>>>(hb, nullptr, eW2, nullptr, nullptr,
                                                     eb2, nullptr, zf, nullptr, 256, 256);
    for (int l=0; l<6; l++){
      const float* Wq = Wqkv + (size_t)l*256*768;
      const float* Wl = Wo   + (size_t)l*256*256;
      const float* W1 = Wff1 + (size_t)l*256*1024;
      const float* W2 = Wff2 + (size_t)l*1024*256;

      ln_v2<<<2048, 256, 0, stream>>>(zf, ln1g+l*256, ln1b+l*256, hb);
      for (int c=0; c<4; c++){
        float* hrows = hb + (size_t)c*2048*256;
        gemm_mfma<0,0,0><<<dim3(6,16), 256, 0, stream>>>(hrows, nullptr, Wq, nullptr, nullptr,
                                                         bqkv+l*768, nullptr, scratch, nullptr, 768, 256);
        attn_v6<<<dim3(4,8,2), 1024, 0, stream>>>(scratch, hrows);
      }
      gemm_mfma<0,0,2><<<dim3(2,64), 256, 0, stream>>>(hb, nullptr, Wl, nullptr, nullptr,
                                                       bo+l*256, zf, zf, nullptr, 256, 256);
      ln_v2<<<2048, 256, 0, stream>>>(zf, ln2g+l*256, ln2b+l*256, hb);
      for (int c=0; c<4; c++){
        float* hrows = hb + (size_t)c*2048*256;
        float* zrows = zf + (size_t)c*2048*256;
        gemm_mfma<0,0,1><<<dim3(8,16), 256, 0, stream>>>(hrows, nullptr, W1, nullptr, nullptr,
                                                         bff1+l*1024, nullptr, scratch, nullptr, 1024, 256);
        gemm_mfma<0,0,2><<<dim3(2,16), 256, 0, stream>>>(scratch, nullptr, W2, nullptr, nullptr,
                                                         bff2+l*256, zrows, zrows, nullptr, 256, 1024);
      }
    }
  }
}